// Round 3
// baseline (1398.419 us; speedup 1.0000x reference)
//
#include <hip/hip_runtime.h>
#include <cstdint>
#include <cstddef>
#include <math.h>

#define IN_F 512
#define OUT_F 1024
#define BATCH 8192
#define W_K 1535   // IN_F + OUT_F - 1
#define SROW 132   // padded t-dimension (16B-aligned rows)

typedef _Float16 half4 __attribute__((ext_vector_type(4)));

// ---------------------------------------------------------------------------
__global__ __launch_bounds__(256) void k_fill(float* __restrict__ out, float val) {
  const size_t i = ((size_t)blockIdx.x * 256 + threadIdx.x) * 4;
  float4 v; v.x = v.y = v.z = v.w = val;
  *(float4*)(out + i) = v;
}

// ---------------------------------------------------------------------------
// K1: xw = x @ Wx.T + bias, OpenBLAS sgemm fp32 semantics. Unchanged.
// ---------------------------------------------------------------------------
__global__ __launch_bounds__(256) void k_gemm32(const float* __restrict__ x,
                                                const float* __restrict__ w,
                                                const float* __restrict__ bias,
                                                float* __restrict__ xw) {
  __shared__ float xs[64][33];
  __shared__ float wsh[64][33];
  const int t = threadIdx.x;
  const int bsub = t >> 4;
  const int esub = t & 15;
  const int bm = blockIdx.x;
  const int bn = blockIdx.y;
  const int srow = t >> 2;
  const int scol = (t & 3) * 8;
  const float* xbase = x + (size_t)(bm * 64 + srow) * IN_F + scol;
  const float* wbase = w + (size_t)(bn * 64 + srow) * W_K + scol;

  float acc[4][4];
#pragma unroll
  for (int a = 0; a < 4; ++a)
#pragma unroll
    for (int b = 0; b < 4; ++b) acc[a][b] = 0.0f;

  for (int k0 = 0; k0 < IN_F; k0 += 32) {
    float xv[8], wv[8];
#pragma unroll
    for (int c = 0; c < 8; ++c) { xv[c] = xbase[k0 + c]; wv[c] = wbase[k0 + c]; }
    __syncthreads();
#pragma unroll
    for (int c = 0; c < 8; ++c) { xs[srow][scol + c] = xv[c]; wsh[srow][scol + c] = wv[c]; }
    __syncthreads();
#pragma unroll
    for (int k = 0; k < 32; ++k) {
      const float a0 = xs[bsub * 4 + 0][k], a1 = xs[bsub * 4 + 1][k];
      const float a2 = xs[bsub * 4 + 2][k], a3 = xs[bsub * 4 + 3][k];
      const float b0 = wsh[esub * 4 + 0][k], b1 = wsh[esub * 4 + 1][k];
      const float b2 = wsh[esub * 4 + 2][k], b3 = wsh[esub * 4 + 3][k];
      acc[0][0] = fmaf(a0, b0, acc[0][0]); acc[0][1] = fmaf(a0, b1, acc[0][1]);
      acc[0][2] = fmaf(a0, b2, acc[0][2]); acc[0][3] = fmaf(a0, b3, acc[0][3]);
      acc[1][0] = fmaf(a1, b0, acc[1][0]); acc[1][1] = fmaf(a1, b1, acc[1][1]);
      acc[1][2] = fmaf(a1, b2, acc[1][2]); acc[1][3] = fmaf(a1, b3, acc[1][3]);
      acc[2][0] = fmaf(a2, b0, acc[2][0]); acc[2][1] = fmaf(a2, b1, acc[2][1]);
      acc[2][2] = fmaf(a2, b2, acc[2][2]); acc[2][3] = fmaf(a2, b3, acc[2][3]);
      acc[3][0] = fmaf(a3, b0, acc[3][0]); acc[3][1] = fmaf(a3, b1, acc[3][1]);
      acc[3][2] = fmaf(a3, b2, acc[3][2]); acc[3][3] = fmaf(a3, b3, acc[3][3]);
    }
  }

#pragma unroll
  for (int ie = 0; ie < 4; ++ie) {
    const int e = bn * 64 + esub * 4 + ie;
    const float bv = bias[e];
#pragma unroll
    for (int ib = 0; ib < 4; ++ib) {
      const int b = bm * 64 + bsub * 4 + ib;
      xw[(size_t)b * OUT_F + e] = acc[ib][ie] + bv;
    }
  }
}

// ---------------------------------------------------------------------------
// helpers: quad_perm DPP adds for the xor2 / xor1 tree levels (cheap VALU,
// bitwise-identical values to __shfl_xor since RNE add is commutative).
// ---------------------------------------------------------------------------
__device__ __forceinline__ float dpp_xor2(float x) {
  int y = __builtin_amdgcn_update_dpp(0, __float_as_int(x), 0x4E, 0xF, 0xF, true);
  return __int_as_float(y);
}
__device__ __forceinline__ float dpp_xor1(float x) {
  int y = __builtin_amdgcn_update_dpp(0, __float_as_int(x), 0xB1, 0xF, 0xF, true);
  return __int_as_float(y);
}
// rth(u) = log2((1-u)/u); +inf for u==0 (always-sample, exact);
// NaN when 1-u rounds to 0 (forces the fp64 guard path).
__device__ __forceinline__ float rth_of(float uu) {
  const float e1 = 1.0f - uu;
  float l1, l2;
  asm("v_log_f32 %0, %1" : "=v"(l1) : "v"(e1));
  asm("v_log_f32 %0, %1" : "=v"(l2) : "v"(uu));
  float rt = l1 - l2;
  if (e1 == 0.0f) rt = __builtin_nanf("");
  return rt;
}

// ---------------------------------------------------------------------------
// K2: scan. Decision by threshold compare (u < sigma(L) <=> -L*log2e <
// log2((1-u)/u)), guarded to be decision-identical to the fp64 sigma path
// (guard band 1e-3 vs <5e-6 measured-bound error; edge cases force guard).
// The dot for L_{i+1} is computed one iteration EARLY (LDS samples <= i-2 +
// register-append of s_{i-1}; omitted/overshot slots are exact +0 identities,
// per-partial ascending chain order preserved). Carried path per step:
// cmp -> select -> fixup FMA -> xor4 swizzle + 2 DPP adds -> add -> mul.
// ---------------------------------------------------------------------------
__global__ __launch_bounds__(64) void k_scan32(const float* __restrict__ w,
                                               const float* __restrict__ u,
                                               const float* __restrict__ xw,
                                               float* __restrict__ out_s,
                                               float* __restrict__ out_l) {
  __shared__ _Float16 smph[8][8][SROW];   // 16.9 KiB sample state (fp16 exact 0/1)
  __shared__ float    wop[8][SROW];       // 4.2 KiB permuted Wo row (j%8, j/8)
  __shared__ float    xwu[2][2][8][32];   // 8 KiB [buf][xw|u][row][step%32]

  const int lane = threadIdx.x;
  const int g = lane >> 3;
  const int m = lane & 7;
  const float NL2E = -1.44269504088896340736f;

  // zero-init sample state (zeros are exact +0 contributions)
  {
    uint32_t* p = (uint32_t*)&smph[0][0][0];
    for (int idx = lane; idx < 8 * 8 * SROW / 2; idx += 64) p[idx] = 0u;
  }

  const int r = blockIdx.x * 8 + g;
  float* osr = out_s + (size_t)r * OUT_F;
  float* olr = out_l + (size_t)r * OUT_F;
  const int rr = blockIdx.x * 8 + (lane >> 3);

  // ---- prologue: xwu chunk 0 -> buf0; chunk 1 -> regs ----
  {
    const float4 xv = *(const float4*)(xw + (size_t)rr * OUT_F + 4 * (lane & 7));
    const float4 uv = *(const float4*)(u  + (size_t)rr * OUT_F + 4 * (lane & 7));
    *(float4*)&xwu[0][0][lane >> 3][4 * (lane & 7)] = xv;
    *(float4*)&xwu[0][1][lane >> 3][4 * (lane & 7)] = uv;
  }
  float4 pxw = *(const float4*)(xw + (size_t)rr * OUT_F + 32 + 4 * (lane & 7));
  float4 pu  = *(const float4*)(u  + (size_t)rr * OUT_F + 32 + 4 * (lane & 7));

  // ---- prologue: Wo row 1 -> wop; then wv <- row 2 ----
  float wv[16];
  {
    const float* wrow = w + (size_t)1 * W_K + IN_F;
#pragma unroll
    for (int c = 0; c < 3; ++c)
      *(float4*)&wv[4 * c] = *(const float4*)(wrow + 4 * lane + 256 * c);
    if (lane < 63) {
      *(float4*)&wv[12] = *(const float4*)(wrow + 4 * lane + 768);
    } else {
      wv[12] = wrow[1020]; wv[13] = wrow[1021]; wv[14] = wrow[1022]; wv[15] = 0.0f;
    }
#pragma unroll
    for (int c = 0; c < 16; ++c) {
      const int j = 4 * lane + 256 * (c >> 2) + (c & 3);
      wop[j & 7][j >> 3] = wv[c];
    }
  }
  {
    const float* wrow = w + (size_t)2 * W_K + IN_F;
#pragma unroll
    for (int c = 0; c < 3; ++c)
      *(float4*)&wv[4 * c] = *(const float4*)(wrow + 4 * lane + 256 * c);
    if (lane < 63) {
      *(float4*)&wv[12] = *(const float4*)(wrow + 4 * lane + 768);
    } else {
      wv[12] = wrow[1020]; wv[13] = wrow[1021]; wv[14] = wrow[1022]; wv[15] = 0.0f;
    }
  }

  // ---- prologue carried state ----
  float L_prev = xwu[0][0][g][0];          // L_0 = xw_0 (+0 dot, exact)
  float u_prev = xwu[0][1][g][0];
  float tneg_prev = L_prev * NL2E;
  float rth_prev = rth_of(u_prev);
  if (m == 0) olr[0] = L_prev;

  float wfix = wop[0][0];                  // w_1[j=0] for L_1's fixup
  float xwh = xwu[0][0][g][1];             // xw_1
  float uh  = xwu[0][1][g][1];             // u_1
  float rth_h = rth_of(uh);

  float P_pre = 0.0f;                      // partials for L_1 (missing j=0)
  float tl[7], tw[7];
#pragma unroll
  for (int jj = 0; jj < 7; ++jj) { tl[jj] = 0.0f; tw[jj] = 0.0f; }

  const half4*  sp = (const half4*)&smph[g][m][0];
  const float4* wp = (const float4*)&wop[m][0];

  for (int i = 1; i < OUT_F; ++i) {
    const int jprev = i - 1;
    const int cph = i & 31;
    const int chunk = i >> 5;

    // --- decision s_{i-1}: threshold compare + rare exact-guard ---
    float s_prev = (tneg_prev < rth_prev) ? 1.0f : 0.0f;
    const float mg = __builtin_fabsf(tneg_prev - rth_prev);
    if (__builtin_expect(!(mg >= 1e-3f), 0)) {
      const double sd = 1.0 / (1.0 + exp(-(double)L_prev));
      s_prev = (u_prev < (float)sd) ? 1.0f : 0.0f;
    }

    // --- finish L_i from last iteration's partials ---
    float P = P_pre;
    if (jprev < 1016)
      P = fmaf((m == (jprev & 7)) ? s_prev : 0.0f, wfix, P);
    float t1 = P + __shfl_xor(P, 4);
    float t2 = t1 + dpp_xor2(t1);
    float T  = t2 + dpp_xor1(t2);
    if (i > 1016) {                        // tail terms can be nonzero only here
      const int ix = jprev - 1016;         // 0..6, static-unrolled update
#pragma unroll
      for (int jj = 0; jj < 7; ++jj) tl[jj] = (jj == ix) ? s_prev : tl[jj];
#pragma unroll
      for (int jj = 0; jj < 7; ++jj) T = fmaf(tl[jj], tw[jj], T);
    }
    const float L = xwh + T;               // np: xw_i + dot (single RNE add)

    if (m == 0) { olr[i] = L; osr[jprev] = s_prev; }

    // --- restage wop <- row i+1 (wv loaded last iter) ---
#pragma unroll
    for (int c = 0; c < 16; ++c) {
      const int j = 4 * lane + 256 * (c >> 2) + (c & 3);
      wop[j & 7][j >> 3] = wv[c];
    }

    // --- hoists for next iteration (row i+1 weights; step i+1 inputs) ---
    const float wapp = wop[jprev & 7][jprev >> 3];  // w_{i+1}[j=i-1] (dot append)
    wfix = wop[i & 7][i >> 3];                      // w_{i+1}[j=i]   (next fixup)
    if (i >= 1016) {
#pragma unroll
      for (int jj = 0; jj < 7; ++jj) tw[jj] = wop[jj][127];   // row i+1 tail wts
    }
    // carried scalars roll forward
    u_prev = uh; rth_prev = rth_h;
    tneg_prev = L * NL2E;
    L_prev = L;
    {
      const int inx = (i + 1 < OUT_F) ? i + 1 : OUT_F - 1;
      xwh = xwu[(inx >> 5) & 1][0][g][inx & 31];
      uh  = xwu[(inx >> 5) & 1][1][g][inx & 31];
      rth_h = rth_of(uh);
    }

    // --- issue wv loads for row i+2 (complete under the dot below) ---
    {
      const int inext = (i + 2 < OUT_F) ? i + 2 : OUT_F - 1;
      const float* wrow = w + (size_t)inext * W_K + IN_F;
#pragma unroll
      for (int c = 0; c < 3; ++c)
        *(float4*)&wv[4 * c] = *(const float4*)(wrow + 4 * lane + 256 * c);
      if (lane < 63) {
        *(float4*)&wv[12] = *(const float4*)(wrow + 4 * lane + 768);
      } else {
        wv[12] = wrow[1020]; wv[13] = wrow[1021]; wv[14] = wrow[1022]; wv[15] = 0.0f;
      }
    }

    // --- xwu chunk management ---
    if (cph == 0) {
      const int cn = chunk + 1;
      const int cbase = (cn < 32 ? cn : 31) * 32;
      pxw = *(const float4*)(xw + (size_t)rr * OUT_F + cbase + 4 * (lane & 7));
      pu  = *(const float4*)(u  + (size_t)rr * OUT_F + cbase + 4 * (lane & 7));
    }
    if (cph == 16) {
      *(float4*)&xwu[(chunk + 1) & 1][0][lane >> 3][4 * (lane & 7)] = pxw;
      *(float4*)&xwu[(chunk + 1) & 1][1][lane >> 3][4 * (lane & 7)] = pu;
    }

    // --- pipelined dot for L_{i+1}: LDS samples <= i-2 (slot i-1 is still 0
    //     in LDS), chunks of 4 quads, over-read slots are exact +0 ---
    const int ilim2 = (i - 1 < 1016) ? (i - 1) : 1016;
    const int tcap = (ilim2 + 7) >> 3;
    const int nch = (tcap + 15) >> 4;
    float Pn = 0.0f;
    for (int ch = 0; ch < nch; ++ch) {
      const half4  s0 = sp[4 * ch + 0], s1 = sp[4 * ch + 1];
      const half4  s2 = sp[4 * ch + 2], s3 = sp[4 * ch + 3];
      const float4 w0 = wp[4 * ch + 0], w1 = wp[4 * ch + 1];
      const float4 w2 = wp[4 * ch + 2], w3 = wp[4 * ch + 3];
      Pn = fmaf((float)s0.x, w0.x, Pn); Pn = fmaf((float)s0.y, w0.y, Pn);
      Pn = fmaf((float)s0.z, w0.z, Pn); Pn = fmaf((float)s0.w, w0.w, Pn);
      Pn = fmaf((float)s1.x, w1.x, Pn); Pn = fmaf((float)s1.y, w1.y, Pn);
      Pn = fmaf((float)s1.z, w1.z, Pn); Pn = fmaf((float)s1.w, w1.w, Pn);
      Pn = fmaf((float)s2.x, w2.x, Pn); Pn = fmaf((float)s2.y, w2.y, Pn);
      Pn = fmaf((float)s2.z, w2.z, Pn); Pn = fmaf((float)s2.w, w2.w, Pn);
      Pn = fmaf((float)s3.x, w3.x, Pn); Pn = fmaf((float)s3.y, w3.y, Pn);
      Pn = fmaf((float)s3.z, w3.z, Pn); Pn = fmaf((float)s3.w, w3.w, Pn);
    }
    // register-append s_{i-1} (last term so far of its partial's chain)
    if (jprev < 1016)
      Pn = fmaf((m == (jprev & 7)) ? s_prev : 0.0f, wapp, Pn);
    P_pre = Pn;

    // sample s_{i-1} -> LDS AFTER the dot reads (so this iteration's dot saw
    // an exact zero there; next iteration's dot reads it from LDS)
    if (m == 0 && jprev < 1016)
      smph[g][jprev & 7][jprev >> 3] = (_Float16)s_prev;
  }

  // epilogue: sample 1023
  {
    float s_l = (tneg_prev < rth_prev) ? 1.0f : 0.0f;
    const float mg = __builtin_fabsf(tneg_prev - rth_prev);
    if (__builtin_expect(!(mg >= 1e-3f), 0)) {
      const double sd = 1.0 / (1.0 + exp(-(double)L_prev));
      s_l = (u_prev < (float)sd) ? 1.0f : 0.0f;
    }
    if (m == 0) osr[OUT_F - 1] = s_l;
  }
}

// ---------------------------------------------------------------------------
extern "C" void kernel_launch(void* const* d_in, const int* in_sizes, int n_in,
                              void* d_out, int out_size, void* d_ws, size_t ws_size,
                              hipStream_t stream) {
  float* out_s = (float*)d_out;                      // samples (B x OUT_F) fp32
  float* out_l = out_s + (size_t)BATCH * OUT_F;      // logits  (B x OUT_F) fp32
  const int nfill = (BATCH * OUT_F) / (256 * 4);

  const bool shapes_ok =
      n_in == 4 &&
      in_sizes[0] == BATCH * IN_F && in_sizes[1] == OUT_F * W_K &&
      in_sizes[2] == OUT_F && in_sizes[3] == BATCH * OUT_F &&
      out_size == 2 * BATCH * OUT_F;
  if (!shapes_ok) {
    k_fill<<<nfill, 256, 0, stream>>>(out_s, 11.0f);
    return;
  }

  const size_t xw_bytes = (size_t)BATCH * OUT_F * sizeof(float);  // 32 MiB
  if (ws_size < xw_bytes) {
    k_fill<<<nfill, 256, 0, stream>>>(out_s, 7.0f);
    return;
  }

  const float* x = (const float*)d_in[0];     // fp32 (8192 x 512)
  const float* w = (const float*)d_in[1];     // fp32 (1024 x 1535)
  const float* bias = (const float*)d_in[2];  // fp32 (1024)
  const float* u = (const float*)d_in[3];     // fp32 (8192 x 1024)
  float* xw = (float*)d_ws;                   // 32 MiB

  k_gemm32<<<dim3(BATCH / 64, OUT_F / 64), 256, 0, stream>>>(x, w, bias, xw);
  k_scan32<<<BATCH / 8, 64, 0, stream>>>(w, u, xw, out_s, out_l);
}

// Round 4
// 1387.118 us; speedup vs baseline: 1.0081x; 1.0081x over previous
//
#include <hip/hip_runtime.h>
#include <cstdint>
#include <cstddef>
#include <math.h>

#define IN_F 512
#define OUT_F 1024
#define BATCH 8192
#define W_K 1535   // IN_F + OUT_F - 1
#define PR 1056    // words per permuted Wo row: 8 partials x 132 (127 data + 5 pad)

// ---------------------------------------------------------------------------
__global__ __launch_bounds__(256) void k_fill(float* __restrict__ out, float val) {
  const size_t i = ((size_t)blockIdx.x * 256 + threadIdx.x) * 4;
  float4 v; v.x = v.y = v.z = v.w = val;
  *(float4*)(out + i) = v;
}

// ---------------------------------------------------------------------------
// K1: xw = x @ Wx.T + bias, OpenBLAS sgemm fp32 semantics. Unchanged, but now
// writes directly into the logits output region (scan consumes it in-place).
// ---------------------------------------------------------------------------
__global__ __launch_bounds__(256) void k_gemm32(const float* __restrict__ x,
                                                const float* __restrict__ w,
                                                const float* __restrict__ bias,
                                                float* __restrict__ xw) {
  __shared__ float xs[64][33];
  __shared__ float wsh[64][33];
  const int t = threadIdx.x;
  const int bsub = t >> 4;
  const int esub = t & 15;
  const int bm = blockIdx.x;
  const int bn = blockIdx.y;
  const int srow = t >> 2;
  const int scol = (t & 3) * 8;
  const float* xbase = x + (size_t)(bm * 64 + srow) * IN_F + scol;
  const float* wbase = w + (size_t)(bn * 64 + srow) * W_K + scol;

  float acc[4][4];
#pragma unroll
  for (int a = 0; a < 4; ++a)
#pragma unroll
    for (int b = 0; b < 4; ++b) acc[a][b] = 0.0f;

  for (int k0 = 0; k0 < IN_F; k0 += 32) {
    float xv[8], wv[8];
#pragma unroll
    for (int c = 0; c < 8; ++c) { xv[c] = xbase[k0 + c]; wv[c] = wbase[k0 + c]; }
    __syncthreads();
#pragma unroll
    for (int c = 0; c < 8; ++c) { xs[srow][scol + c] = xv[c]; wsh[srow][scol + c] = wv[c]; }
    __syncthreads();
#pragma unroll
    for (int k = 0; k < 32; ++k) {
      const float a0 = xs[bsub * 4 + 0][k], a1 = xs[bsub * 4 + 1][k];
      const float a2 = xs[bsub * 4 + 2][k], a3 = xs[bsub * 4 + 3][k];
      const float b0 = wsh[esub * 4 + 0][k], b1 = wsh[esub * 4 + 1][k];
      const float b2 = wsh[esub * 4 + 2][k], b3 = wsh[esub * 4 + 3][k];
      acc[0][0] = fmaf(a0, b0, acc[0][0]); acc[0][1] = fmaf(a0, b1, acc[0][1]);
      acc[0][2] = fmaf(a0, b2, acc[0][2]); acc[0][3] = fmaf(a0, b3, acc[0][3]);
      acc[1][0] = fmaf(a1, b0, acc[1][0]); acc[1][1] = fmaf(a1, b1, acc[1][1]);
      acc[1][2] = fmaf(a1, b2, acc[1][2]); acc[1][3] = fmaf(a1, b3, acc[1][3]);
      acc[2][0] = fmaf(a2, b0, acc[2][0]); acc[2][1] = fmaf(a2, b1, acc[2][1]);
      acc[2][2] = fmaf(a2, b2, acc[2][2]); acc[2][3] = fmaf(a2, b3, acc[2][3]);
      acc[3][0] = fmaf(a3, b0, acc[3][0]); acc[3][1] = fmaf(a3, b1, acc[3][1]);
      acc[3][2] = fmaf(a3, b2, acc[3][2]); acc[3][3] = fmaf(a3, b3, acc[3][3]);
    }
  }

#pragma unroll
  for (int ie = 0; ie < 4; ++ie) {
    const int e = bn * 64 + esub * 4 + ie;
    const float bv = bias[e];
#pragma unroll
    for (int ib = 0; ib < 4; ++ib) {
      const int b = bm * 64 + bsub * 4 + ib;
      xw[(size_t)b * OUT_F + e] = acc[ib][ie] + bv;
    }
  }
}

// ---------------------------------------------------------------------------
// K_perm: one-time permute of the Wo region into scan-friendly layout:
//   wPerm[i][m*132 + t] = Wo[i][m + 8t]   (vector region j < 1016)
//   wTail[i][0..6]      = Wo[i][1016..1022], wTail[i][7] = 0
//   pad slots t in [127,132) zeroed.
// ---------------------------------------------------------------------------
__global__ __launch_bounds__(256) void k_perm(const float* __restrict__ w,
                                              float* __restrict__ wPerm,
                                              float* __restrict__ wTail) {
  const int i = blockIdx.x;
  const int t = threadIdx.x;
  const float* src = w + (size_t)i * W_K + IN_F;
  float* drow = wPerm + (size_t)i * PR;
#pragma unroll
  for (int c = 0; c < 4; ++c) {
    const int j = t + 256 * c;
    const float v = (j < OUT_F - 1) ? src[j] : 0.0f;
    if (j < 1016) drow[(j & 7) * 132 + (j >> 3)] = v;
    else if (j < OUT_F - 1) wTail[i * 8 + (j - 1016)] = v;
    else wTail[i * 8 + 7] = 0.0f;
  }
  if (t < 40) drow[(t / 5) * 132 + 127 + (t % 5)] = 0.0f;
}

// ---------------------------------------------------------------------------
// cross-lane helpers (bitwise-identical values; RNE add commutes)
// ---------------------------------------------------------------------------
__device__ __forceinline__ float dpp_xor2(float x) {
  int y = __builtin_amdgcn_update_dpp(0, __float_as_int(x), 0x4E, 0xF, 0xF, true);
  return __int_as_float(y);
}
__device__ __forceinline__ float dpp_xor1(float x) {
  int y = __builtin_amdgcn_update_dpp(0, __float_as_int(x), 0xB1, 0xF, 0xF, true);
  return __int_as_float(y);
}
// rth(u) = log2((1-u)/u); +inf for u==0; NaN when 1-u rounds to 0 (forces guard)
__device__ __forceinline__ float rth_of(float uu) {
  const float e1 = 1.0f - uu;
  float l1, l2;
  asm("v_log_f32 %0, %1" : "=v"(l1) : "v"(e1));
  asm("v_log_f32 %0, %1" : "=v"(l2) : "v"(uu));
  float rt = l1 - l2;
  if (e1 == 0.0f) rt = __builtin_nanf("");
  return rt;
}

#define LOADQ(P, CH) { const int _q = 4 * (CH); \
  P##s0 = spq[_q]; P##s1 = spq[_q + 1]; P##s2 = spq[_q + 2]; P##s3 = spq[_q + 3]; \
  P##w0 = wpq[_q]; P##w1 = wpq[_q + 1]; P##w2 = wpq[_q + 2]; P##w3 = wpq[_q + 3]; }

#define FMAQ(P) { \
  Pn = fmaf(P##s0.x, P##w0.x, Pn); Pn = fmaf(P##s0.y, P##w0.y, Pn); \
  Pn = fmaf(P##s0.z, P##w0.z, Pn); Pn = fmaf(P##s0.w, P##w0.w, Pn); \
  Pn = fmaf(P##s1.x, P##w1.x, Pn); Pn = fmaf(P##s1.y, P##w1.y, Pn); \
  Pn = fmaf(P##s1.z, P##w1.z, Pn); Pn = fmaf(P##s1.w, P##w1.w, Pn); \
  Pn = fmaf(P##s2.x, P##w2.x, Pn); Pn = fmaf(P##s2.y, P##w2.y, Pn); \
  Pn = fmaf(P##s2.z, P##w2.z, Pn); Pn = fmaf(P##s2.w, P##w2.w, Pn); \
  Pn = fmaf(P##s3.x, P##w3.x, Pn); Pn = fmaf(P##s3.y, P##w3.y, Pn); \
  Pn = fmaf(P##s3.z, P##w3.z, Pn); Pn = fmaf(P##s3.w, P##w3.w, Pn); }

#define WVLOAD(P, ROW) { const float4* _gq = (const float4*)(wPerm + (size_t)(ROW) * PR); \
  P##0 = _gq[lane]; P##1 = _gq[lane + 64]; P##2 = _gq[lane + 128]; P##3 = _gq[lane + 192]; \
  P##4 = _gq[256 + (lane & 7)]; }

#define RESTAGE(P) { float4* _wq = (float4*)wop; \
  _wq[lane] = P##0; _wq[lane + 64] = P##1; _wq[lane + 128] = P##2; _wq[lane + 192] = P##3; \
  if (lane < 8) _wq[256 + lane] = P##4; }

// ---------------------------------------------------------------------------
// K2: scan. Same arithmetic chain as the passing r3 kernel (mod-8 partials
// ascending-j FMA with exact +0 identities for absent slots, register
// append/fixup at chain end, AVX tree, threshold decision with fp64 guard).
// Restructured data supply:
//  - wop holds Wo row i+1 a full iteration before the dot reads it (restage
//    at iter i writes row i+2 from wv regs loaded at iter i-1).
//  - samples fp32 in LDS, b128 reads, conflict-free layout; no cvts.
//  - dot hand-pipelined 1-ahead (A/B chunk sets), chunk0 preloaded at the
//    previous iteration's end.
//  - wfix/wapp/tail weights prefetched from GLOBAL one iteration ahead; the
//    carried path never reads freshly-written LDS.
//  - xw read in-place from the logits buffer (read [i+1] precedes write [i+1]).
// ---------------------------------------------------------------------------
__global__ __launch_bounds__(64, 1) void k_scan32(const float* __restrict__ w,
                                                  const float* __restrict__ u,
                                                  const float* __restrict__ wPerm,
                                                  const float* __restrict__ wTail,
                                                  float* xwl,
                                                  float* __restrict__ out_s) {
  __shared__ __align__(16) float smp[8 * PR];   // 33.0 KiB fp32 samples
  __shared__ __align__(16) float wop[PR];       //  4.1 KiB current Wo row

  const int lane = threadIdx.x;
  const int g = lane >> 3;   // row group 0..7
  const int m = lane & 7;    // partial index
  const float NL2E = -1.44269504088896340736f;

  // zero-init samples (exact +0 contributions)
  {
    float4 z; z.x = z.y = z.z = z.w = 0.0f;
    float4* smpq = (float4*)smp;
    for (int q = lane; q < (8 * PR) / 4; q += 64) smpq[q] = z;
  }

  const int r = blockIdx.x * 8 + g;
  float* xwl_row = xwl + (size_t)r * OUT_F;       // xw in, logits out (in-place)
  const float* uro = u + (size_t)r * OUT_F;
  float* osr = out_s + (size_t)r * OUT_F;

  float4 wvA0, wvA1, wvA2, wvA3, wvA4, wvB0, wvB1, wvB2, wvB3, wvB4;
  float4 As0, As1, As2, As3, Aw0, Aw1, Aw2, Aw3;
  float4 Bs0, Bs1, Bs2, Bs3, Bw0, Bw1, Bw2, Bw3;

  // ---- prologue: wop <- row 2 (dot at iter 1 computes L_2's partials);
  //      wvA <- row 3 (restaged at iter 1) ----
  WVLOAD(wvB, 2);
  RESTAGE(wvB);
  WVLOAD(wvA, 3);

  // carried scalars
  float L_prev = xwl_row[0];                 // L_0 = xw_0 (empty dot; buffer
  float u_prev = uro[0];                     // already holds it -> no store)
  float tneg_prev = L_prev * NL2E;
  float rth_prev = rth_of(u_prev);
  float xwh_c = xwl_row[1];
  float uh_c = uro[1];
  float rth_c = rth_of(uh_c);
  float wfix_c = w[(size_t)1 * W_K + IN_F + 0];   // w_1[j=0]
  float wapp_c = w[(size_t)2 * W_K + IN_F + 0];   // w_2[j=0]
  float P_pre = 0.0f;
  float tl[7], tw[7];
#pragma unroll
  for (int jj = 0; jj < 7; ++jj) { tl[jj] = 0.0f; tw[jj] = 0.0f; }

  const float4* spq = (const float4*)(smp + g * PR + m * 132);
  const float4* wpq = (const float4*)(wop + m * 132);

  LOADQ(A, 0);   // chunk 0 for iteration 1 (zeros)

  for (int i = 1; i < OUT_F; ++i) {
    const int jprev = i - 1;

    // 1) decision s_{i-1}: threshold compare + rare exact fp64 guard
    float s_prev = (tneg_prev < rth_prev) ? 1.0f : 0.0f;
    const float mg = __builtin_fabsf(tneg_prev - rth_prev);
    if (__builtin_expect(!(mg >= 1e-3f), 0)) {
      const double sd = 1.0 / (1.0 + exp(-(double)L_prev));
      s_prev = (u_prev < (float)sd) ? 1.0f : 0.0f;
    }

    // 2) finish L_i from last iteration's partials
    float P = P_pre;
    if (jprev < 1016)
      P = fmaf((m == (jprev & 7)) ? s_prev : 0.0f, wfix_c, P);
    float t1 = P + __shfl_xor(P, 4);
    float t2 = t1 + dpp_xor2(t1);
    float T  = t2 + dpp_xor1(t2);
    if (i > 1016) {
      const int ix = jprev - 1016;
#pragma unroll
      for (int jj = 0; jj < 7; ++jj) tl[jj] = (jj == ix) ? s_prev : tl[jj];
#pragma unroll
      for (int jj = 0; jj < 7; ++jj) T = fmaf(tl[jj], tw[jj], T);
    }
    const float L = xwh_c + T;                 // np: xw_i + dot (single RNE add)

    // 3) stores
    if (m == 0) { xwl_row[i] = L; osr[jprev] = s_prev; }

    // 4) roll + prefetch next-iteration scalars (global, 1-iter slack)
    u_prev = uh_c; rth_prev = rth_c;
    L_prev = L; tneg_prev = L * NL2E;
    {
      const int inx = (i + 1 < OUT_F) ? i + 1 : OUT_F - 1;
      xwh_c = xwl_row[inx];
      const float uu = uro[inx];
      uh_c = uu; rth_c = rth_of(uu);
      wfix_c = w[(size_t)inx * W_K + IN_F + i];        // w_{i+1}[j=i]
      if (i >= 1016) {
#pragma unroll
        for (int jj = 0; jj < 7; ++jj) tw[jj] = wTail[inx * 8 + jj];
      }
    }
    // issue next wPerm row loads (row i+3, consumed at iter i+1's restage)
    {
      const int rown = (i + 3 < OUT_F) ? i + 3 : OUT_F - 1;
      if (i & 1) { WVLOAD(wvB, rown); } else { WVLOAD(wvA, rown); }
    }

    // 5) pipelined dot for L_{i+1}: LDS samples <= i-2 (+0 elsewhere), wop
    //    holds row i+1 (staged a full iteration ago). 1-ahead A/B chunks.
    const int ilim2 = (i - 1 < 1016) ? (i - 1) : 1016;
    const int tcap = (ilim2 + 7) >> 3;
    const int nch = (tcap + 15) >> 4;
    float Pn = 0.0f;
    int ch = 0;
    for (; ch + 2 <= nch; ch += 2) {
      LOADQ(B, ch + 1);
      FMAQ(A);
      if (ch + 2 < nch) LOADQ(A, ch + 2);
      FMAQ(B);
    }
    if (ch < nch) FMAQ(A);

    // 6) register-append s_{i-1}·w_{i+1}[j=i-1] (chain-end identity position)
    if (jprev < 1016)
      Pn = fmaf((m == (jprev & 7)) ? s_prev : 0.0f, wapp_c, Pn);
    wapp_c = w[(size_t)((i + 2 < OUT_F) ? i + 2 : OUT_F - 1) * W_K + IN_F + i];

    // 7) restage wop <- row i+2 (all row-i+1 reads issued above; LDS is
    //    in-order per wave, so reads return old data)
    if (i & 1) { RESTAGE(wvA); } else { RESTAGE(wvB); }

    // 8) publish sample (this iter's dot saw exact zero there)
    if (m == 0 && jprev < 1016)
      smp[g * PR + (jprev & 7) * 132 + (jprev >> 3)] = s_prev;

    // 9) preload chunk 0 for next iteration (reads row i+2 + fresh sample)
    LOADQ(A, 0);

    // 10) carry partials
    P_pre = Pn;
  }

  // epilogue: sample 1023
  {
    float s_l = (tneg_prev < rth_prev) ? 1.0f : 0.0f;
    const float mg = __builtin_fabsf(tneg_prev - rth_prev);
    if (__builtin_expect(!(mg >= 1e-3f), 0)) {
      const double sd = 1.0 / (1.0 + exp(-(double)L_prev));
      s_l = (u_prev < (float)sd) ? 1.0f : 0.0f;
    }
    if (m == 0) osr[OUT_F - 1] = s_l;
  }
}

// ---------------------------------------------------------------------------
extern "C" void kernel_launch(void* const* d_in, const int* in_sizes, int n_in,
                              void* d_out, int out_size, void* d_ws, size_t ws_size,
                              hipStream_t stream) {
  float* out_s = (float*)d_out;                      // samples (B x OUT_F) fp32
  float* out_l = out_s + (size_t)BATCH * OUT_F;      // logits  (B x OUT_F) fp32
  const int nfill = (BATCH * OUT_F) / (256 * 4);

  const bool shapes_ok =
      n_in == 4 &&
      in_sizes[0] == BATCH * IN_F && in_sizes[1] == OUT_F * W_K &&
      in_sizes[2] == OUT_F && in_sizes[3] == BATCH * OUT_F &&
      out_size == 2 * BATCH * OUT_F;
  if (!shapes_ok) {
    k_fill<<<nfill, 256, 0, stream>>>(out_s, 11.0f);
    return;
  }

  const size_t perm_bytes = ((size_t)OUT_F * PR + (size_t)OUT_F * 8) * sizeof(float);
  if (ws_size < perm_bytes) {
    k_fill<<<nfill, 256, 0, stream>>>(out_s, 7.0f);
    return;
  }

  const float* x = (const float*)d_in[0];     // fp32 (8192 x 512)
  const float* w = (const float*)d_in[1];     // fp32 (1024 x 1535)
  const float* bias = (const float*)d_in[2];  // fp32 (1024)
  const float* u = (const float*)d_in[3];     // fp32 (8192 x 1024)
  float* wPerm = (float*)d_ws;                          // 4.2 MiB
  float* wTail = wPerm + (size_t)OUT_F * PR;            // 32 KiB

  k_gemm32<<<dim3(BATCH / 64, OUT_F / 64), 256, 0, stream>>>(x, w, bias, out_l);
  k_perm<<<OUT_F, 256, 0, stream>>>(w, wPerm, wTail);
  k_scan32<<<BATCH / 8, 64, 0, stream>>>(w, u, wPerm, wTail, out_l, out_s);
}

// Round 5
// 1009.364 us; speedup vs baseline: 1.3854x; 1.3742x over previous
//
#include <hip/hip_runtime.h>
#include <cstdint>
#include <cstddef>
#include <math.h>

#define IN_F 512
#define OUT_F 1024
#define BATCH 8192
#define W_K 1535   // IN_F + OUT_F - 1
#define PR 1056    // floats per wPerm row: 8 partials x 132 (127 data + 5 pad)
#define SR16 136   // halves per partial-row in smp (16B-aligned stride)
#define GS16 (8 * SR16)   // halves per row-group (1088)

typedef _Float16 half8 __attribute__((ext_vector_type(8)));

__device__ __forceinline__ int imin(int a, int b) { return a < b ? a : b; }
__device__ __forceinline__ int imax(int a, int b) { return a > b ? a : b; }

// ---------------------------------------------------------------------------
__global__ __launch_bounds__(256) void k_fill(float* __restrict__ out, float val) {
  const size_t i = ((size_t)blockIdx.x * 256 + threadIdx.x) * 4;
  float4 v; v.x = v.y = v.z = v.w = val;
  *(float4*)(out + i) = v;
}

// ---------------------------------------------------------------------------
// K1: xw = x @ Wx.T + bias, OpenBLAS sgemm fp32 semantics. Unchanged.
// Writes into the logits output region (scan consumes/overwrites in place).
// ---------------------------------------------------------------------------
__global__ __launch_bounds__(256) void k_gemm32(const float* __restrict__ x,
                                                const float* __restrict__ w,
                                                const float* __restrict__ bias,
                                                float* __restrict__ xw) {
  __shared__ float xs[64][33];
  __shared__ float wsh[64][33];
  const int t = threadIdx.x;
  const int bsub = t >> 4;
  const int esub = t & 15;
  const int bm = blockIdx.x;
  const int bn = blockIdx.y;
  const int srow = t >> 2;
  const int scol = (t & 3) * 8;
  const float* xbase = x + (size_t)(bm * 64 + srow) * IN_F + scol;
  const float* wbase = w + (size_t)(bn * 64 + srow) * W_K + scol;

  float acc[4][4];
#pragma unroll
  for (int a = 0; a < 4; ++a)
#pragma unroll
    for (int b = 0; b < 4; ++b) acc[a][b] = 0.0f;

  for (int k0 = 0; k0 < IN_F; k0 += 32) {
    float xv[8], wv[8];
#pragma unroll
    for (int c = 0; c < 8; ++c) { xv[c] = xbase[k0 + c]; wv[c] = wbase[k0 + c]; }
    __syncthreads();
#pragma unroll
    for (int c = 0; c < 8; ++c) { xs[srow][scol + c] = xv[c]; wsh[srow][scol + c] = wv[c]; }
    __syncthreads();
#pragma unroll
    for (int k = 0; k < 32; ++k) {
      const float a0 = xs[bsub * 4 + 0][k], a1 = xs[bsub * 4 + 1][k];
      const float a2 = xs[bsub * 4 + 2][k], a3 = xs[bsub * 4 + 3][k];
      const float b0 = wsh[esub * 4 + 0][k], b1 = wsh[esub * 4 + 1][k];
      const float b2 = wsh[esub * 4 + 2][k], b3 = wsh[esub * 4 + 3][k];
      acc[0][0] = fmaf(a0, b0, acc[0][0]); acc[0][1] = fmaf(a0, b1, acc[0][1]);
      acc[0][2] = fmaf(a0, b2, acc[0][2]); acc[0][3] = fmaf(a0, b3, acc[0][3]);
      acc[1][0] = fmaf(a1, b0, acc[1][0]); acc[1][1] = fmaf(a1, b1, acc[1][1]);
      acc[1][2] = fmaf(a1, b2, acc[1][2]); acc[1][3] = fmaf(a1, b3, acc[1][3]);
      acc[2][0] = fmaf(a2, b0, acc[2][0]); acc[2][1] = fmaf(a2, b1, acc[2][1]);
      acc[2][2] = fmaf(a2, b2, acc[2][2]); acc[2][3] = fmaf(a2, b3, acc[2][3]);
      acc[3][0] = fmaf(a3, b0, acc[3][0]); acc[3][1] = fmaf(a3, b1, acc[3][1]);
      acc[3][2] = fmaf(a3, b2, acc[3][2]); acc[3][3] = fmaf(a3, b3, acc[3][3]);
    }
  }

#pragma unroll
  for (int ie = 0; ie < 4; ++ie) {
    const int e = bn * 64 + esub * 4 + ie;
    const float bv = bias[e];
#pragma unroll
    for (int ib = 0; ib < 4; ++ib) {
      const int b = bm * 64 + bsub * 4 + ib;
      xw[(size_t)b * OUT_F + e] = acc[ib][ie] + bv;
    }
  }
}

// ---------------------------------------------------------------------------
// K_perm: wPerm[i][m*132 + t] = Wo[i][m + 8t] (vector region j < 1016);
// wTail[i][0..6] = Wo[i][1016..1022]; pads zeroed. Unchanged.
// ---------------------------------------------------------------------------
__global__ __launch_bounds__(256) void k_perm(const float* __restrict__ w,
                                              float* __restrict__ wPerm,
                                              float* __restrict__ wTail) {
  const int i = blockIdx.x;
  const int t = threadIdx.x;
  const float* src = w + (size_t)i * W_K + IN_F;
  float* drow = wPerm + (size_t)i * PR;
#pragma unroll
  for (int c = 0; c < 4; ++c) {
    const int j = t + 256 * c;
    const float v = (j < OUT_F - 1) ? src[j] : 0.0f;
    if (j < 1016) drow[(j & 7) * 132 + (j >> 3)] = v;
    else if (j < OUT_F - 1) wTail[i * 8 + (j - 1016)] = v;
    else wTail[i * 8 + 7] = 0.0f;
  }
  if (t < 40) drow[(t / 5) * 132 + 127 + (t % 5)] = 0.0f;
}

// ---------------------------------------------------------------------------
// helpers (bitwise-identical values; RNE add commutes)
// ---------------------------------------------------------------------------
__device__ __forceinline__ float dpp_xor2(float x) {
  int y = __builtin_amdgcn_update_dpp(0, __float_as_int(x), 0x4E, 0xF, 0xF, true);
  return __int_as_float(y);
}
__device__ __forceinline__ float dpp_xor1(float x) {
  int y = __builtin_amdgcn_update_dpp(0, __float_as_int(x), 0xB1, 0xF, 0xF, true);
  return __int_as_float(y);
}
__device__ __forceinline__ float rth_of(float uu) {
  const float e1 = 1.0f - uu;
  float l1, l2;
  asm("v_log_f32 %0, %1" : "=v"(l1) : "v"(e1));
  asm("v_log_f32 %0, %1" : "=v"(l2) : "v"(uu));
  float rt = l1 - l2;
  if (e1 == 0.0f) rt = __builtin_nanf("");
  return rt;
}
// threshold decision, decision-identical to fp64 sigma (guard band 1e-3 vs
// <5e-6 bound; edge cases yield NaN margin -> guard path)
__device__ __forceinline__ float decide(float L, float uu, float rth) {
  const float NL2E = -1.44269504088896340736f;
  const float tneg = L * NL2E;
  float s = (tneg < rth) ? 1.0f : 0.0f;
  const float mg = __builtin_fabsf(tneg - rth);
  if (__builtin_expect(!(mg >= 1e-3f), 0)) {
    const double sd = 1.0 / (1.0 + exp(-(double)L));
    s = (uu < (float)sd) ? 1.0f : 0.0f;
  }
  return s;
}
__device__ __forceinline__ float tree8(float P) {
  float t1 = P + __shfl_xor(P, 4);
  float t2 = t1 + dpp_xor2(t1);
  return t2 + dpp_xor1(t2);
}
__device__ __forceinline__ void tl_upd(float (&tl)[7], int j, float s) {
  if (j >= 1016 && j < 1023) {
    const int ix = j - 1016;
#pragma unroll
    for (int jj = 0; jj < 7; ++jj) tl[jj] = (jj == ix) ? s : tl[jj];
  }
}
// append term j at chain end (exact: all skipped slots contributed exact +0)
__device__ __forceinline__ float append_j(float P, int j, float s, float wgt, int m) {
  if (j >= 0 && j < 1016) P = fmaf((m == (j & 7)) ? s : 0.0f, wgt, P);
  return P;
}
// dot over LDS state: NL valid terms; over-read slots are unpublished zeros
__device__ __forceinline__ float dot_nl(const _Float16* sp, const float* wp, int NL) {
  const int tcap = (NL + 7) >> 3;
  const int nch = (tcap + 15) >> 4;
  float P = 0.0f;
  for (int ch = 0; ch < nch; ++ch) {
    const half8 s0 = *(const half8*)(sp + 16 * ch);
    const half8 s1 = *(const half8*)(sp + 16 * ch + 8);
    const float4 w0 = *(const float4*)(wp + 16 * ch);
    const float4 w1 = *(const float4*)(wp + 16 * ch + 4);
    const float4 w2 = *(const float4*)(wp + 16 * ch + 8);
    const float4 w3 = *(const float4*)(wp + 16 * ch + 12);
    P = fmaf((float)s0[0], w0.x, P); P = fmaf((float)s0[1], w0.y, P);
    P = fmaf((float)s0[2], w0.z, P); P = fmaf((float)s0[3], w0.w, P);
    P = fmaf((float)s0[4], w1.x, P); P = fmaf((float)s0[5], w1.y, P);
    P = fmaf((float)s0[6], w1.z, P); P = fmaf((float)s0[7], w1.w, P);
    P = fmaf((float)s1[0], w2.x, P); P = fmaf((float)s1[1], w2.y, P);
    P = fmaf((float)s1[2], w2.z, P); P = fmaf((float)s1[3], w2.w, P);
    P = fmaf((float)s1[4], w3.x, P); P = fmaf((float)s1[5], w3.y, P);
    P = fmaf((float)s1[6], w3.z, P); P = fmaf((float)s1[7], w3.w, P);
  }
  return P;
}
// raw barrier: LDS-ordering only (no vmcnt drain; cross-wave data is LDS-only)
__device__ __forceinline__ void block_sync_lds() {
  asm volatile("s_waitcnt lgkmcnt(0)" ::: "memory");
  __builtin_amdgcn_s_barrier();
  asm volatile("" ::: "memory");
}

#define WVLOAD(ROW) { const float4* _gq = (const float4*)(wPerm + (size_t)(ROW) * PR); \
  wv0 = _gq[lane]; wv1 = _gq[lane + 64]; wv2 = _gq[lane + 128]; wv3 = _gq[lane + 192]; \
  wv4 = _gq[256 + (lane & 7)]; }
#define RESTAGE(DST) { float4* _wq = (float4*)(DST); \
  _wq[lane] = wv0; _wq[lane + 64] = wv1; _wq[lane + 128] = wv2; _wq[lane + 192] = wv3; \
  if (lane < 8) _wq[256 + lane] = wv4; }

// ---------------------------------------------------------------------------
// K2: 2-wave step-parallel scan. Both waves share the same 8 rows; wave0
// executes odd steps, wave1 even steps. Per iteration k (steps 2k-1, 2k):
//  phase1: both dots over LDS samples <= 2k-4 (+ register fixups for the
//          2-3 most recent terms, appended in ascending j at chain end —
//          exact +0 identities elsewhere). wave0 finishes L_{2k-1}, decides
//          s_{2k-1}, mailboxes it. wave1 stages its next W row.
//  barrier (LDS-only).
//  phase2: wave1 appends fresh s_{2k-1}, finishes L_{2k}, decides, mailboxes.
//          Both waves publish their PREVIOUS decisions (slots 2k-3, 2k-2) to
//          smp — so phase1 over-reads always saw exact zeros. wave0 stages.
//  barrier.
// Arithmetic chain is bit-identical to the r4 kernel (same partial order,
// tree, tail, single RNE adds, threshold+fp64-guard decisions).
// ---------------------------------------------------------------------------
__global__ __launch_bounds__(128, 3) void k_scan32(const float* __restrict__ w,
                                                   const float* __restrict__ u,
                                                   const float* __restrict__ wPerm,
                                                   const float* __restrict__ wTail,
                                                   float* xwl,
                                                   float* __restrict__ out_s) {
  __shared__ __align__(16) _Float16 smp[8 * GS16];  // 17408 B, fp16 samples
  __shared__ __align__(16) float wop[2][PR];        //  8448 B, per-wave W row
  __shared__ float mb0[8], mb1[8];                  // decision mailboxes

  const int tid = threadIdx.x;
  const int wid = tid >> 6;
  const int lane = tid & 63;
  const int g = lane >> 3, m = lane & 7;

  // zero sample state (exact +0 contributions until published)
  {
    uint4 z; z.x = z.y = z.z = z.w = 0u;
    uint4* p = (uint4*)smp;
    for (int q = tid; q < (8 * GS16) / 8; q += 128) p[q] = z;
  }

  const int r = blockIdx.x * 8 + g;
  float* xwl_row = xwl + (size_t)r * OUT_F;   // xw in, logits out (in place)
  const float* uro = u + (size_t)r * OUT_F;
  float* osr = out_s + (size_t)r * OUT_F;

  const _Float16* sp = smp + g * GS16 + m * SR16;
  const float* wp = &wop[wid][m * 132];

  float4 wv0, wv1, wv2, wv3, wv4;
  float s_last = 0.0f, s_pp = 0.0f, s_new = 0.0f, Pc = 0.0f;
  float xwh = 0.0f, uh = 0.0f, rth = 0.0f;
  float wgt0 = 0.0f, wgt1 = 0.0f, wgt2 = 0.0f;
  float tl[7], tw[7];
#pragma unroll
  for (int jj = 0; jj < 7; ++jj) { tl[jj] = 0.0f; tw[jj] = 0.0f; }

  // ---- prologue ----
  if (wid == 1) {
    // step 0: L_0 = xw_0 (already in xwl_row[0]; no store needed)
    const float L0 = xwl_row[0];
    const float u0 = uro[0];
    const float s0 = decide(L0, u0, rth_of(u0));
    if (m == 0) { osr[0] = s0; mb1[g] = s0; }
    s_last = s0;
    xwh = xwl_row[2]; uh = uro[2]; rth = rth_of(uh);
    wgt1 = w[(size_t)2 * W_K + IN_F + 0];   // w_2[j=0]
    wgt2 = w[(size_t)2 * W_K + IN_F + 1];   // w_2[j=1]
    WVLOAD(4);
  } else {
    xwh = xwl_row[1]; uh = uro[1]; rth = rth_of(uh);
    wgt1 = w[(size_t)1 * W_K + IN_F + 0];   // w_1[j=0]
    WVLOAD(3);
  }
  __syncthreads();

  for (int k = 1; k <= 512; ++k) {
    const int NL = imin(imax(2 * k - 3, 0), 1016);
    // ================= PHASE 1 =================
    if (wid == 0) {
      const int i = 2 * k - 1;
      const float s_part = mb1[g];            // s_{2k-2} (prev iter, barriered)
      tl_upd(tl, i - 2, s_last);
      tl_upd(tl, i - 1, s_part);
      float P = dot_nl(sp, wp, NL);
      P = append_j(P, i - 2, s_last, wgt0, m);
      P = append_j(P, i - 1, s_part, wgt1, m);
      float T = tree8(P);
      if (i > 1016) {
#pragma unroll
        for (int jj = 0; jj < 7; ++jj) T = fmaf(tl[jj], tw[jj], T);
      }
      const float L = xwh + T;                // np: xw_i + dot (single RNE add)
      s_new = decide(L, uh, rth);
      if (m == 0) { xwl_row[i] = L; osr[i] = s_new; mb0[g] = s_new; }
    } else if (k <= 511) {
      const int i = 2 * k;
      tl_upd(tl, i - 3, s_pp);
      tl_upd(tl, i - 2, s_last);
      float P = dot_nl(sp, wp, NL);
      P = append_j(P, i - 3, s_pp, wgt0, m);
      P = append_j(P, i - 2, s_last, wgt1, m);
      Pc = P;
      // stage my next W row (i+2 = 2k+2; wv loaded last iteration)
      RESTAGE(wop[1]);
      WVLOAD(imin(2 * k + 4, OUT_F - 1));
    }
    block_sync_lds();
    // ================= PHASE 2 =================
    if (wid == 0) {
      // publish previous decision (slot 2k-3) — dots only read in phase1
      const int jp = 2 * k - 3;
      if (jp >= 0 && jp < 1016 && m == 0)
        smp[g * GS16 + (jp & 7) * SR16 + (jp >> 3)] = (_Float16)s_last;
      s_last = s_new;
      // stage my next W row (2k+1; wv loaded last iteration)
      RESTAGE(wop[0]);
      WVLOAD(imin(2 * k + 3, OUT_F - 1));
      // prefetch scalars for my next step i' = 2k+1
      const int rown = imin(2 * k + 1, OUT_F - 1);
      xwh = xwl_row[rown]; uh = uro[rown]; rth = rth_of(uh);
      wgt0 = w[(size_t)rown * W_K + IN_F + imin(2 * k - 1, 1022)];  // j=i'-2
      wgt1 = w[(size_t)rown * W_K + IN_F + imin(2 * k, 1022)];      // j=i'-1
      if (2 * k + 1 > 1016) {
#pragma unroll
        for (int jj = 0; jj < 7; ++jj) tw[jj] = wTail[rown * 8 + jj];
      }
    } else if (k <= 511) {
      const int i = 2 * k;
      const float s_fresh = mb0[g];           // s_{2k-1} (after barrier)
      tl_upd(tl, i - 1, s_fresh);
      float P = append_j(Pc, i - 1, s_fresh, wgt2, m);
      float T = tree8(P);
      if (i > 1016) {
#pragma unroll
        for (int jj = 0; jj < 7; ++jj) T = fmaf(tl[jj], tw[jj], T);
      }
      const float L = xwh + T;
      s_new = decide(L, uh, rth);
      if (m == 0) { xwl_row[i] = L; osr[i] = s_new; mb1[g] = s_new; }
      // publish previous decision (slot 2k-2)
      const int jp = 2 * k - 2;
      if (jp < 1016 && m == 0)
        smp[g * GS16 + (jp & 7) * SR16 + (jp >> 3)] = (_Float16)s_last;
      s_pp = s_fresh; s_last = s_new;
      // prefetch scalars for my next step i' = 2k+2
      const int rown = imin(2 * k + 2, OUT_F - 1);
      xwh = xwl_row[rown]; uh = uro[rown]; rth = rth_of(uh);
      wgt0 = w[(size_t)rown * W_K + IN_F + imin(2 * k - 1, 1022)];  // j=i'-3
      wgt1 = w[(size_t)rown * W_K + IN_F + imin(2 * k, 1022)];      // j=i'-2
      wgt2 = w[(size_t)rown * W_K + IN_F + imin(2 * k + 1, 1022)];  // j=i'-1
      if (2 * k + 2 > 1016) {
#pragma unroll
        for (int jj = 0; jj < 7; ++jj) tw[jj] = wTail[rown * 8 + jj];
      }
    }
    block_sync_lds();
  }
}

// ---------------------------------------------------------------------------
extern "C" void kernel_launch(void* const* d_in, const int* in_sizes, int n_in,
                              void* d_out, int out_size, void* d_ws, size_t ws_size,
                              hipStream_t stream) {
  float* out_s = (float*)d_out;                      // samples (B x OUT_F) fp32
  float* out_l = out_s + (size_t)BATCH * OUT_F;      // logits  (B x OUT_F) fp32
  const int nfill = (BATCH * OUT_F) / (256 * 4);

  const bool shapes_ok =
      n_in == 4 &&
      in_sizes[0] == BATCH * IN_F && in_sizes[1] == OUT_F * W_K &&
      in_sizes[2] == OUT_F && in_sizes[3] == BATCH * OUT_F &&
      out_size == 2 * BATCH * OUT_F;
  if (!shapes_ok) {
    k_fill<<<nfill, 256, 0, stream>>>(out_s, 11.0f);
    return;
  }

  const size_t perm_bytes = ((size_t)OUT_F * PR + (size_t)OUT_F * 8) * sizeof(float);
  if (ws_size < perm_bytes) {
    k_fill<<<nfill, 256, 0, stream>>>(out_s, 7.0f);
    return;
  }

  const float* x = (const float*)d_in[0];     // fp32 (8192 x 512)
  const float* w = (const float*)d_in[1];     // fp32 (1024 x 1535)
  const float* bias = (const float*)d_in[2];  // fp32 (1024)
  const float* u = (const float*)d_in[3];     // fp32 (8192 x 1024)
  float* wPerm = (float*)d_ws;                          // 4.2 MiB
  float* wTail = wPerm + (size_t)OUT_F * PR;            // 32 KiB

  k_gemm32<<<dim3(BATCH / 64, OUT_F / 64), 256, 0, stream>>>(x, w, bias, out_l);
  k_perm<<<OUT_F, 256, 0, stream>>>(w, wPerm, wTail);
  k_scan32<<<BATCH / 8, 128, 0, stream>>>(w, u, wPerm, wTail, out_l, out_s);
}

// Round 6
// 890.118 us; speedup vs baseline: 1.5710x; 1.1340x over previous
//
#include <hip/hip_runtime.h>
#include <cstdint>
#include <cstddef>
#include <math.h>

#define IN_F 512
#define OUT_F 1024
#define BATCH 8192
#define W_K 1535   // IN_F + OUT_F - 1
#define PR 1056    // floats per wPerm row: 8 partials x 132 (127 data + 5 pad)

typedef _Float16 h4 __attribute__((ext_vector_type(4)));

#define F4C(v, c) ((c) == 0 ? (v).x : (c) == 1 ? (v).y : (c) == 2 ? (v).z : (v).w)

// ---------------------------------------------------------------------------
__global__ __launch_bounds__(256) void k_fill(float* __restrict__ out, float val) {
  const size_t i = ((size_t)blockIdx.x * 256 + threadIdx.x) * 4;
  float4 v; v.x = v.y = v.z = v.w = val;
  *(float4*)(out + i) = v;
}

// ---------------------------------------------------------------------------
// K1: xw = x @ Wx.T + bias, OpenBLAS sgemm fp32 semantics. Unchanged.
// Writes into the logits output region (scan consumes/overwrites in place).
// ---------------------------------------------------------------------------
__global__ __launch_bounds__(256) void k_gemm32(const float* __restrict__ x,
                                                const float* __restrict__ w,
                                                const float* __restrict__ bias,
                                                float* __restrict__ xw) {
  __shared__ float xs[64][33];
  __shared__ float wsh[64][33];
  const int t = threadIdx.x;
  const int bsub = t >> 4;
  const int esub = t & 15;
  const int bm = blockIdx.x;
  const int bn = blockIdx.y;
  const int srow = t >> 2;
  const int scol = (t & 3) * 8;
  const float* xbase = x + (size_t)(bm * 64 + srow) * IN_F + scol;
  const float* wbase = w + (size_t)(bn * 64 + srow) * W_K + scol;

  float acc[4][4];
#pragma unroll
  for (int a = 0; a < 4; ++a)
#pragma unroll
    for (int b = 0; b < 4; ++b) acc[a][b] = 0.0f;

  for (int k0 = 0; k0 < IN_F; k0 += 32) {
    float xv[8], wv[8];
#pragma unroll
    for (int c = 0; c < 8; ++c) { xv[c] = xbase[k0 + c]; wv[c] = wbase[k0 + c]; }
    __syncthreads();
#pragma unroll
    for (int c = 0; c < 8; ++c) { xs[srow][scol + c] = xv[c]; wsh[srow][scol + c] = wv[c]; }
    __syncthreads();
#pragma unroll
    for (int k = 0; k < 32; ++k) {
      const float a0 = xs[bsub * 4 + 0][k], a1 = xs[bsub * 4 + 1][k];
      const float a2 = xs[bsub * 4 + 2][k], a3 = xs[bsub * 4 + 3][k];
      const float b0 = wsh[esub * 4 + 0][k], b1 = wsh[esub * 4 + 1][k];
      const float b2 = wsh[esub * 4 + 2][k], b3 = wsh[esub * 4 + 3][k];
      acc[0][0] = fmaf(a0, b0, acc[0][0]); acc[0][1] = fmaf(a0, b1, acc[0][1]);
      acc[0][2] = fmaf(a0, b2, acc[0][2]); acc[0][3] = fmaf(a0, b3, acc[0][3]);
      acc[1][0] = fmaf(a1, b0, acc[1][0]); acc[1][1] = fmaf(a1, b1, acc[1][1]);
      acc[1][2] = fmaf(a1, b2, acc[1][2]); acc[1][3] = fmaf(a1, b3, acc[1][3]);
      acc[2][0] = fmaf(a2, b0, acc[2][0]); acc[2][1] = fmaf(a2, b1, acc[2][1]);
      acc[2][2] = fmaf(a2, b2, acc[2][2]); acc[2][3] = fmaf(a2, b3, acc[2][3]);
      acc[3][0] = fmaf(a3, b0, acc[3][0]); acc[3][1] = fmaf(a3, b1, acc[3][1]);
      acc[3][2] = fmaf(a3, b2, acc[3][2]); acc[3][3] = fmaf(a3, b3, acc[3][3]);
    }
  }

#pragma unroll
  for (int ie = 0; ie < 4; ++ie) {
    const int e = bn * 64 + esub * 4 + ie;
    const float bv = bias[e];
#pragma unroll
    for (int ib = 0; ib < 4; ++ib) {
      const int b = bm * 64 + bsub * 4 + ib;
      xw[(size_t)b * OUT_F + e] = acc[ib][ie] + bv;
    }
  }
}

// ---------------------------------------------------------------------------
// K_perm: wPerm[i][m*132 + t] = Wo[i][m + 8t] (vector region j < 1016);
// wTail[i][0..6] = Wo[i][1016..1022]; pads zeroed. Unchanged.
// ---------------------------------------------------------------------------
__global__ __launch_bounds__(256) void k_perm(const float* __restrict__ w,
                                              float* __restrict__ wPerm,
                                              float* __restrict__ wTail) {
  const int i = blockIdx.x;
  const int t = threadIdx.x;
  const float* src = w + (size_t)i * W_K + IN_F;
  float* drow = wPerm + (size_t)i * PR;
#pragma unroll
  for (int c = 0; c < 4; ++c) {
    const int j = t + 256 * c;
    const float v = (j < OUT_F - 1) ? src[j] : 0.0f;
    if (j < 1016) drow[(j & 7) * 132 + (j >> 3)] = v;
    else if (j < OUT_F - 1) wTail[i * 8 + (j - 1016)] = v;
    else wTail[i * 8 + 7] = 0.0f;
  }
  if (t < 40) drow[(t / 5) * 132 + 127 + (t % 5)] = 0.0f;
}

// ---------------------------------------------------------------------------
// helpers (bitwise-identical values; RNE add commutes)
// ---------------------------------------------------------------------------
__device__ __forceinline__ float dpp_xor2(float x) {
  int y = __builtin_amdgcn_update_dpp(0, __float_as_int(x), 0x4E, 0xF, 0xF, true);
  return __int_as_float(y);
}
__device__ __forceinline__ float dpp_xor1(float x) {
  int y = __builtin_amdgcn_update_dpp(0, __float_as_int(x), 0xB1, 0xF, 0xF, true);
  return __int_as_float(y);
}
__device__ __forceinline__ float rth_of(float uu) {
  const float e1 = 1.0f - uu;
  float l1, l2;
  asm("v_log_f32 %0, %1" : "=v"(l1) : "v"(e1));
  asm("v_log_f32 %0, %1" : "=v"(l2) : "v"(uu));
  float rt = l1 - l2;
  if (e1 == 0.0f) rt = __builtin_nanf("");
  return rt;
}
// raw barrier: LDS ordering only (cross-wave data is LDS-only; globals are
// single-owner) — vmcnt NOT drained so prefetches stay in flight.
__device__ __forceinline__ void block_sync_lds() {
  asm volatile("s_waitcnt lgkmcnt(0)" ::: "memory");
  __builtin_amdgcn_s_barrier();
  asm volatile("" ::: "memory");
}

// ---------------------------------------------------------------------------
// One scan step i = 32*PH + 8*A + B  (A,B compile-time; PH may be runtime).
// Chain for L_i (bit-identical to the monolithic reference chain):
//   P = OldP(i)                                  [fold j < 32(PH-1), from LDS]
//   + ps terms (prev block, c'=0..3, ascending)  [j = 32(PH-1)+m+8c']
//   + cs terms (cur block, ascending, validity-masked: absent = exact +0)
//   + append j = i-1 on lane (i-1)&7 with s_prev [last term of its chain]
//   -> AVX tree -> L = xw_i + T -> threshold decision (fp64-guard, rare).
// ---------------------------------------------------------------------------
#define SCAN_STEP(PH, A, B) do {                                               \
    if ((B) == 0)                                                              \
      opq[1] = *(const float4*)&oldp[(PH) & 1][2 * (A) + 1][g][m][0];          \
    if ((B) == 4 && (A) < 3)                                                   \
      opq[0] = *(const float4*)&oldp[(PH) & 1][2 * (A) + 2][g][m][0];          \
    const int i_ = 32 * (PH) + 8 * (A) + (B);                                  \
    float P_ = F4C(opq[((B) >> 2) & 1], (B) & 3);                              \
    {                                                                          \
      const float4 wl_ = wlo[(B) & 3];                                         \
      P_ = fmaf(ps[0], wl_.x, P_);                                             \
      P_ = fmaf(ps[1], wl_.y, P_);                                             \
      P_ = fmaf(ps[2], wl_.z, P_);                                             \
      if ((A) == 0 && (B) == 0) P_ = fmaf((m < 7) ? ps[3] : 0.0f, wl_.w, P_);  \
      else                      P_ = fmaf(ps[3], wl_.w, P_);                   \
    }                                                                          \
    {                                                                          \
      const float4 wh_ = whi[(B) & 3];                                         \
      if ((A) >= 1) {                                                          \
        if ((A) == 1 && (B) == 0) P_ = fmaf((m < 7) ? cs[0] : 0.0f, wh_.x, P_);\
        else                      P_ = fmaf(cs[0], wh_.x, P_);                 \
      }                                                                        \
      if ((A) >= 2) {                                                          \
        if ((A) == 2 && (B) == 0) P_ = fmaf((m < 7) ? cs[1] : 0.0f, wh_.y, P_);\
        else                      P_ = fmaf(cs[1], wh_.y, P_);                 \
      }                                                                        \
      if ((A) >= 3) {                                                          \
        if ((A) == 3 && (B) == 0) P_ = fmaf((m < 7) ? cs[2] : 0.0f, wh_.z, P_);\
        else                      P_ = fmaf(cs[2], wh_.z, P_);                 \
      }                                                                        \
      if ((B) >= 2)                                                            \
        P_ = fmaf((m < (B) - 1) ? cs[(A)] : 0.0f, F4C(wh_, (A)), P_);          \
    }                                                                          \
    P_ = fmaf((m == (((B) + 7) & 7)) ? s_prev : 0.0f, wapp[(B) & 3], P_);      \
    float t1_ = P_ + __shfl_xor(P_, 4);                                        \
    float t2_ = t1_ + dpp_xor2(t1_);                                           \
    const float T_ = t2_ + dpp_xor1(t2_);                                      \
    const float L_ = xwh[(B) & 1] + T_;                                        \
    const float tneg_ = L_ * NL2E;                                             \
    float s_ = (tneg_ < rth_cur) ? 1.0f : 0.0f;                                \
    const float mg_ = __builtin_fabsf(tneg_ - rth_cur);                        \
    if (__builtin_expect(!(mg_ >= 1e-3f), 0)) {                                \
      const double sd_ = 1.0 / (1.0 + exp(-(double)L_));                       \
      s_ = (uu[(B) & 1] < (float)sd_) ? 1.0f : 0.0f;                           \
    }                                                                          \
    if (m == 0) { xwl_row[i_] = L_; osr[i_] = s_; }                            \
    cs[(A)] = (m == (B)) ? s_ : cs[(A)];                                       \
    s_prev = s_;                                                               \
    rth_cur = rth_of(uu[((B) + 1) & 1]);                                       \
    {                                                                          \
      const int nx2_ = (i_ + 2 < OUT_F) ? i_ + 2 : OUT_F - 1;                  \
      xwh[(B) & 1] = xwl_row[nx2_];                                            \
      uu[(B) & 1] = uro[nx2_];                                                 \
    }                                                                          \
    {                                                                          \
      const int nx4_ = (i_ + 4 < OUT_F) ? i_ + 4 : OUT_F - 1;                  \
      const int th_ = (nx4_ >> 5) * 4;                                         \
      const int tlo_ = (th_ >= 4) ? th_ - 4 : 0;                               \
      const float* wr_ = wPermRow + (size_t)nx4_ * PR;                         \
      wlo[(B) & 3] = *(const float4*)(wr_ + tlo_);                             \
      whi[(B) & 3] = *(const float4*)(wr_ + th_);                              \
      wapp[(B) & 3] = wAppBase[(size_t)nx4_ * (W_K + 1)];                      \
    }                                                                          \
  } while (0)

#define SCAN_GROUP(PH, A) do {                                                 \
    SCAN_STEP(PH, A, 0); SCAN_STEP(PH, A, 1);                                  \
    SCAN_STEP(PH, A, 2); SCAN_STEP(PH, A, 3);                                  \
    SCAN_STEP(PH, A, 4); SCAN_STEP(PH, A, 5);                                  \
    SCAN_STEP(PH, A, 6); SCAN_STEP(PH, A, 7);                                  \
  } while (0)

// tail steps i = 1017..1023: vector region complete (no j=i-1 vector append);
// tail js 1016..i-1 appended to T ascending, tl[io] = s_{1016+io}.
#define SPEC_STEP(IO) do {                                                     \
    const int i_ = 1017 + (IO);                                                \
    const int o_ = 25 + (IO);                                                  \
    float P_ = F4C(opq[(o_ >> 2) & 1], o_ & 3);                                \
    {                                                                          \
      const float4 wl_ = wlo[o_ & 3];                                          \
      P_ = fmaf(ps[0], wl_.x, P_); P_ = fmaf(ps[1], wl_.y, P_);                \
      P_ = fmaf(ps[2], wl_.z, P_); P_ = fmaf(ps[3], wl_.w, P_);                \
    }                                                                          \
    {                                                                          \
      const float4 wh_ = whi[o_ & 3];                                          \
      P_ = fmaf(cs[0], wh_.x, P_); P_ = fmaf(cs[1], wh_.y, P_);                \
      P_ = fmaf(cs[2], wh_.z, P_);                                             \
    }                                                                          \
    float t1_ = P_ + __shfl_xor(P_, 4);                                        \
    float t2_ = t1_ + dpp_xor2(t1_);                                           \
    float T_ = t2_ + dpp_xor1(t2_);                                            \
    tl[(IO)] = s_prev;                                                         \
    T_ = fmaf(tl[0], twa.x, T_);                                               \
    if ((IO) >= 1) T_ = fmaf(tl[1], twa.y, T_);                                \
    if ((IO) >= 2) T_ = fmaf(tl[2], twa.z, T_);                                \
    if ((IO) >= 3) T_ = fmaf(tl[3], twa.w, T_);                                \
    if ((IO) >= 4) T_ = fmaf(tl[4], twb.x, T_);                                \
    if ((IO) >= 5) T_ = fmaf(tl[5], twb.y, T_);                                \
    if ((IO) >= 6) T_ = fmaf(tl[6], twb.z, T_);                                \
    const float L_ = xwh[o_ & 1] + T_;                                         \
    const float tneg_ = L_ * NL2E;                                             \
    float s_ = (tneg_ < rth_cur) ? 1.0f : 0.0f;                                \
    const float mg_ = __builtin_fabsf(tneg_ - rth_cur);                        \
    if (__builtin_expect(!(mg_ >= 1e-3f), 0)) {                                \
      const double sd_ = 1.0 / (1.0 + exp(-(double)L_));                       \
      s_ = (uu[o_ & 1] < (float)sd_) ? 1.0f : 0.0f;                            \
    }                                                                          \
    if (m == 0) { xwl_row[i_] = L_; osr[i_] = s_; }                            \
    s_prev = s_;                                                               \
    rth_cur = rth_of(uu[(o_ + 1) & 1]);                                        \
    {                                                                          \
      const int nx2_ = (i_ + 2 < OUT_F) ? i_ + 2 : OUT_F - 1;                  \
      xwh[o_ & 1] = xwl_row[nx2_]; uu[o_ & 1] = uro[nx2_];                     \
    }                                                                          \
    {                                                                          \
      const int nx4_ = (i_ + 4 < OUT_F) ? i_ + 4 : OUT_F - 1;                  \
      const float* wr_ = wPermRow + (size_t)nx4_ * PR;                         \
      wlo[o_ & 3] = *(const float4*)(wr_ + 120);                               \
      whi[o_ & 3] = *(const float4*)(wr_ + 124);                               \
    }                                                                          \
    if ((IO) < 6) {                                                            \
      twa = *(const float4*)(wTail + (i_ + 1) * 8);                            \
      twb = *(const float4*)(wTail + (i_ + 1) * 8 + 4);                        \
    }                                                                          \
  } while (0)

// ---------------------------------------------------------------------------
// K2: checkpointed scan. 4 waves/block, 8 rows/block, 32-step phases.
//  wave 0 (scan): per step, chain = OldP(i) [LDS] + <=8 register recent terms
//   + append + tree + threshold decision. Samples held in lane-local regs;
//   published to smph once per phase. One barrier per phase (32 total).
//  waves 1-3 (bulk): during phase p, compute OldP checkpoints for block p+1
//   (sequential ascending-t folds over published samples j < 32p) — exact
//   prefixes of the reference partial chains, embarrassingly parallel.
// LDS: smph 16K + oldp dbuf 16K = 32K -> 4 blocks/CU (grid = 1024 = exactly
// resident). Bit-exact: same term sequence per partial, same tree/tail/
// decision arithmetic as the previously-passing kernels.
// ---------------------------------------------------------------------------
__global__ __launch_bounds__(256) void k_scan32(const float* __restrict__ w,
                                                const float* __restrict__ u,
                                                const float* __restrict__ wPerm,
                                                const float* __restrict__ wTail,
                                                float* xwl,
                                                float* __restrict__ out_s) {
  __shared__ _Float16 smph[8][128][8];    // [m][t][r] samples, 16 KiB
  __shared__ float oldp[2][8][8][8][4];   // [buf][quad][g][m][c], 16 KiB

  const int tid = threadIdx.x;
  const int wid = tid >> 6;
  const int lane = tid & 63;
  const int g = lane >> 3, m = lane & 7;
  const float NL2E = -1.44269504088896340736f;

  // zero OldP buf0 (block-0 chains start at 0); buf1 is fully written by
  // bulk in phase 0. smph needs no init (only published regions are read).
  {
    float* z = &oldp[0][0][0][0][0];
#pragma unroll
    for (int k = 0; k < 8; ++k) z[tid + 256 * k] = 0.0f;
  }
  __syncthreads();

  const int r = blockIdx.x * 8 + g;
  float* xwl_row = xwl + (size_t)r * OUT_F;   // xw in, logits out (in place)
  const float* uro = u + (size_t)r * OUT_F;
  float* osr = out_s + (size_t)r * OUT_F;

  // scan state (live only on wave 0; unified regalloc makes this harmless)
  float4 wlo[4], whi[4], opq[2];
  float wapp[4], xwh[2], uu[2];
  float ps[4], cs[4], tl[7];
  float rth_cur = 0.0f, s_prev = 0.0f;
  const float* wPermRow = wPerm + m * 132;
  const float* wAppBase = w + (IN_F - 1);   // wAppBase[i*(W_K+1)] = w[i][512+i-1]
  const int bl = (wid - 1) * 64 + lane;     // bulk lane id (wid >= 1)

  if (wid == 0) {
#pragma unroll
    for (int c = 0; c < 4; ++c) { ps[c] = 0.0f; cs[c] = 0.0f; }
#pragma unroll
    for (int c = 0; c < 7; ++c) tl[c] = 0.0f;
#pragma unroll
    for (int b = 0; b < 4; ++b) {
      const float* wr_ = wPermRow + (size_t)b * PR;
      wlo[b] = *(const float4*)(wr_);     // p=0: ps unused (zeros, exact +0)
      whi[b] = *(const float4*)(wr_);     // t_hi = 0 for phase 0
      wapp[b] = (b == 0) ? 0.0f : wAppBase[(size_t)b * (W_K + 1)];
    }
    xwh[0] = xwl_row[0]; xwh[1] = xwl_row[1];
    uu[0] = uro[0]; uu[1] = uro[1];
    rth_cur = rth_of(uu[0]);
  }

  for (int p = 0; p < 31; ++p) {
    if (wid == 0) {
      // -------- scan phase p: steps 32p .. 32p+31 --------
      opq[0] = *(const float4*)&oldp[p & 1][0][g][m][0];
      SCAN_GROUP(p, 0); SCAN_GROUP(p, 1); SCAN_GROUP(p, 2); SCAN_GROUP(p, 3);
      // publish this block's samples (t = 4p..4p+3) and roll
#pragma unroll
      for (int k = 0; k < 4; ++k)
        smph[m][4 * p + k][g] = (_Float16)cs[k];
#pragma unroll
      for (int k = 0; k < 4; ++k) ps[k] = cs[k];
    } else {
      // -------- bulk: OldP checkpoints for block p+1 (fold t < 4p) --------
      const int buf = (p + 1) & 1;
      for (int q = bl; q < 256; q += 192) {
        const int mq = q >> 5;
        const int iop = (q & 31) >> 1;   // i-pair index 0..15
        const int rh = q & 1;            // row half
        const int i0 = 32 * (p + 1) + iop * 2;
        float a00 = 0, a01 = 0, a02 = 0, a03 = 0;
        float a10 = 0, a11 = 0, a12 = 0, a13 = 0;
        const _Float16* sb = &smph[mq][0][rh * 4];
        const float* w0 = wPerm + (size_t)i0 * PR + mq * 132;
        const float* w1 = w0 + PR;
#pragma unroll 2
        for (int t4 = 0; t4 < p; ++t4) {
          const float4 wa = *(const float4*)(w0 + 4 * t4);
          const float4 wb = *(const float4*)(w1 + 4 * t4);
#pragma unroll
          for (int tt = 0; tt < 4; ++tt) {
            const h4 sv = *(const h4*)(sb + (4 * t4 + tt) * 8);
            const float s0 = (float)sv[0], s1 = (float)sv[1];
            const float s2 = (float)sv[2], s3 = (float)sv[3];
            const float wA = F4C(wa, tt), wB = F4C(wb, tt);
            a00 = fmaf(s0, wA, a00); a01 = fmaf(s1, wA, a01);
            a02 = fmaf(s2, wA, a02); a03 = fmaf(s3, wA, a03);
            a10 = fmaf(s0, wB, a10); a11 = fmaf(s1, wB, a11);
            a12 = fmaf(s2, wB, a12); a13 = fmaf(s3, wB, a13);
          }
        }
        const int qd = (iop * 2) >> 2, c0 = (iop * 2) & 3;   // c0 in {0,2}
        oldp[buf][qd][rh * 4 + 0][mq][c0] = a00;
        oldp[buf][qd][rh * 4 + 1][mq][c0] = a01;
        oldp[buf][qd][rh * 4 + 2][mq][c0] = a02;
        oldp[buf][qd][rh * 4 + 3][mq][c0] = a03;
        oldp[buf][qd][rh * 4 + 0][mq][c0 + 1] = a10;
        oldp[buf][qd][rh * 4 + 1][mq][c0 + 1] = a11;
        oldp[buf][qd][rh * 4 + 2][mq][c0 + 1] = a12;
        oldp[buf][qd][rh * 4 + 3][mq][c0 + 1] = a13;
      }
    }
    block_sync_lds();
  }

  if (wid == 0) {
    // -------- phase 31: steps 992..1015 generic, 1016 generic, tail special
    opq[0] = *(const float4*)&oldp[1][0][g][m][0];
    SCAN_GROUP(31, 0); SCAN_GROUP(31, 1); SCAN_GROUP(31, 2);
    SCAN_STEP(31, 3, 0);   // i = 1016 (chain j=1015 is still vector-region)
    float4 twa = *(const float4*)(wTail + 1017 * 8);
    float4 twb = *(const float4*)(wTail + 1017 * 8 + 4);
    SPEC_STEP(0); SPEC_STEP(1); SPEC_STEP(2); SPEC_STEP(3);
    SPEC_STEP(4); SPEC_STEP(5); SPEC_STEP(6);
  }
}

// ---------------------------------------------------------------------------
extern "C" void kernel_launch(void* const* d_in, const int* in_sizes, int n_in,
                              void* d_out, int out_size, void* d_ws, size_t ws_size,
                              hipStream_t stream) {
  float* out_s = (float*)d_out;                      // samples (B x OUT_F) fp32
  float* out_l = out_s + (size_t)BATCH * OUT_F;      // logits  (B x OUT_F) fp32
  const int nfill = (BATCH * OUT_F) / (256 * 4);

  const bool shapes_ok =
      n_in == 4 &&
      in_sizes[0] == BATCH * IN_F && in_sizes[1] == OUT_F * W_K &&
      in_sizes[2] == OUT_F && in_sizes[3] == BATCH * OUT_F &&
      out_size == 2 * BATCH * OUT_F;
  if (!shapes_ok) {
    k_fill<<<nfill, 256, 0, stream>>>(out_s, 11.0f);
    return;
  }

  const size_t perm_bytes = ((size_t)OUT_F * PR + (size_t)OUT_F * 8) * sizeof(float);
  if (ws_size < perm_bytes) {
    k_fill<<<nfill, 256, 0, stream>>>(out_s, 7.0f);
    return;
  }

  const float* x = (const float*)d_in[0];     // fp32 (8192 x 512)
  const float* w = (const float*)d_in[1];     // fp32 (1024 x 1535)
  const float* bias = (const float*)d_in[2];  // fp32 (1024)
  const float* u = (const float*)d_in[3];     // fp32 (8192 x 1024)
  float* wPerm = (float*)d_ws;                          // 4.2 MiB
  float* wTail = wPerm + (size_t)OUT_F * PR;            // 32 KiB

  k_gemm32<<<dim3(BATCH / 64, OUT_F / 64), 256, 0, stream>>>(x, w, bias, out_l);
  k_perm<<<OUT_F, 256, 0, stream>>>(w, wPerm, wTail);
  k_scan32<<<BATCH / 8, 256, 0, stream>>>(w, u, wPerm, wTail, out_l, out_s);
}

// Round 7
// 808.959 us; speedup vs baseline: 1.7287x; 1.1003x over previous
//
#include <hip/hip_runtime.h>
#include <cstdint>
#include <cstddef>
#include <math.h>

#define IN_F 512
#define OUT_F 1024
#define BATCH 8192
#define W_K 1535   // IN_F + OUT_F - 1
#define PR 1056    // floats per wPerm row: 8 partials x 132 (127 data + 5 pad)
#define ROWS 16    // batch rows per block
#define SR 136     // halves per (r,m) sample row (b64-aligned, bank-spread)

typedef _Float16 h4 __attribute__((ext_vector_type(4)));

#define F4C(v, c) ((c) == 0 ? (v).x : (c) == 1 ? (v).y : (c) == 2 ? (v).z : (v).w)

// ---------------------------------------------------------------------------
__global__ __launch_bounds__(256) void k_fill(float* __restrict__ out, float val) {
  const size_t i = ((size_t)blockIdx.x * 256 + threadIdx.x) * 4;
  float4 v; v.x = v.y = v.z = v.w = val;
  *(float4*)(out + i) = v;
}

// ---------------------------------------------------------------------------
// K1: xw = x @ Wx.T + bias, OpenBLAS sgemm fp32 semantics. Unchanged.
// ---------------------------------------------------------------------------
__global__ __launch_bounds__(256) void k_gemm32(const float* __restrict__ x,
                                                const float* __restrict__ w,
                                                const float* __restrict__ bias,
                                                float* __restrict__ xw) {
  __shared__ float xs[64][33];
  __shared__ float wsh[64][33];
  const int t = threadIdx.x;
  const int bsub = t >> 4;
  const int esub = t & 15;
  const int bm = blockIdx.x;
  const int bn = blockIdx.y;
  const int srow = t >> 2;
  const int scol = (t & 3) * 8;
  const float* xbase = x + (size_t)(bm * 64 + srow) * IN_F + scol;
  const float* wbase = w + (size_t)(bn * 64 + srow) * W_K + scol;

  float acc[4][4];
#pragma unroll
  for (int a = 0; a < 4; ++a)
#pragma unroll
    for (int b = 0; b < 4; ++b) acc[a][b] = 0.0f;

  for (int k0 = 0; k0 < IN_F; k0 += 32) {
    float xv[8], wv[8];
#pragma unroll
    for (int c = 0; c < 8; ++c) { xv[c] = xbase[k0 + c]; wv[c] = wbase[k0 + c]; }
    __syncthreads();
#pragma unroll
    for (int c = 0; c < 8; ++c) { xs[srow][scol + c] = xv[c]; wsh[srow][scol + c] = wv[c]; }
    __syncthreads();
#pragma unroll
    for (int k = 0; k < 32; ++k) {
      const float a0 = xs[bsub * 4 + 0][k], a1 = xs[bsub * 4 + 1][k];
      const float a2 = xs[bsub * 4 + 2][k], a3 = xs[bsub * 4 + 3][k];
      const float b0 = wsh[esub * 4 + 0][k], b1 = wsh[esub * 4 + 1][k];
      const float b2 = wsh[esub * 4 + 2][k], b3 = wsh[esub * 4 + 3][k];
      acc[0][0] = fmaf(a0, b0, acc[0][0]); acc[0][1] = fmaf(a0, b1, acc[0][1]);
      acc[0][2] = fmaf(a0, b2, acc[0][2]); acc[0][3] = fmaf(a0, b3, acc[0][3]);
      acc[1][0] = fmaf(a1, b0, acc[1][0]); acc[1][1] = fmaf(a1, b1, acc[1][1]);
      acc[1][2] = fmaf(a1, b2, acc[1][2]); acc[1][3] = fmaf(a1, b3, acc[1][3]);
      acc[2][0] = fmaf(a2, b0, acc[2][0]); acc[2][1] = fmaf(a2, b1, acc[2][1]);
      acc[2][2] = fmaf(a2, b2, acc[2][2]); acc[2][3] = fmaf(a2, b3, acc[2][3]);
      acc[3][0] = fmaf(a3, b0, acc[3][0]); acc[3][1] = fmaf(a3, b1, acc[3][1]);
      acc[3][2] = fmaf(a3, b2, acc[3][2]); acc[3][3] = fmaf(a3, b3, acc[3][3]);
    }
  }

#pragma unroll
  for (int ie = 0; ie < 4; ++ie) {
    const int e = bn * 64 + esub * 4 + ie;
    const float bv = bias[e];
#pragma unroll
    for (int ib = 0; ib < 4; ++ib) {
      const int b = bm * 64 + bsub * 4 + ib;
      xw[(size_t)b * OUT_F + e] = acc[ib][ie] + bv;
    }
  }
}

// ---------------------------------------------------------------------------
// K_perm: wPerm[i][m*132 + t] = Wo[i][m + 8t] (scan layout);
//         wPermT[t][i][m]     = Wo[i][m + 8t] (bulk layout, coalesced);
//         wTail[i][0..6]      = Wo[i][1016..1022]; pads zeroed.
// ---------------------------------------------------------------------------
__global__ __launch_bounds__(256) void k_perm(const float* __restrict__ w,
                                              float* __restrict__ wPerm,
                                              float* __restrict__ wTail,
                                              float* __restrict__ wPermT) {
  const int i = blockIdx.x;
  const int t = threadIdx.x;
  const float* src = w + (size_t)i * W_K + IN_F;
  float* drow = wPerm + (size_t)i * PR;
#pragma unroll
  for (int c = 0; c < 4; ++c) {
    const int j = t + 256 * c;
    const float v = (j < OUT_F - 1) ? src[j] : 0.0f;
    if (j < 1016) {
      drow[(j & 7) * 132 + (j >> 3)] = v;
      wPermT[(size_t)(j >> 3) * (OUT_F * 8) + i * 8 + (j & 7)] = v;
    } else if (j < OUT_F - 1) wTail[i * 8 + (j - 1016)] = v;
    else wTail[i * 8 + 7] = 0.0f;
  }
  if (t < 40) drow[(t / 5) * 132 + 127 + (t % 5)] = 0.0f;
}

// ---------------------------------------------------------------------------
// helpers (bitwise-identical values; RNE add commutes)
// ---------------------------------------------------------------------------
__device__ __forceinline__ float dpp_xor2(float x) {
  int y = __builtin_amdgcn_update_dpp(0, __float_as_int(x), 0x4E, 0xF, 0xF, true);
  return __int_as_float(y);
}
__device__ __forceinline__ float dpp_xor1(float x) {
  int y = __builtin_amdgcn_update_dpp(0, __float_as_int(x), 0xB1, 0xF, 0xF, true);
  return __int_as_float(y);
}
__device__ __forceinline__ float rth_of(float uu) {
  const float e1 = 1.0f - uu;
  float l1, l2;
  asm("v_log_f32 %0, %1" : "=v"(l1) : "v"(e1));
  asm("v_log_f32 %0, %1" : "=v"(l2) : "v"(uu));
  float rt = l1 - l2;
  if (e1 == 0.0f) rt = __builtin_nanf("");
  return rt;
}
// raw barrier: LDS ordering only (cross-wave data is LDS-only; globals are
// single-owner) — vmcnt NOT drained so prefetches stay in flight.
__device__ __forceinline__ void block_sync_lds() {
  asm volatile("s_waitcnt lgkmcnt(0)" ::: "memory");
  __builtin_amdgcn_s_barrier();
  asm volatile("" ::: "memory");
}

// ---------------------------------------------------------------------------
// One scan step i = 32*PH + 8*A + B (A,B compile-time). Chain for L_i is the
// exact reference chain: P = OldP(i) [LDS] + ps terms + masked cs terms
// (absent = exact +0) + append j=i-1 -> tree -> L -> threshold decision
// (fp64-guard, rare). Verified structure from r6 (passing).
// ---------------------------------------------------------------------------
#define SCAN_STEP(PH, A, B) do {                                               \
    if ((B) == 0)                                                              \
      opq[1] = *(const float4*)&oldp[(PH) & 1][2 * (A) + 1][rl][m][0];         \
    if ((B) == 4 && (A) < 3)                                                   \
      opq[0] = *(const float4*)&oldp[(PH) & 1][2 * (A) + 2][rl][m][0];         \
    const int i_ = 32 * (PH) + 8 * (A) + (B);                                  \
    float P_ = F4C(opq[((B) >> 2) & 1], (B) & 3);                              \
    {                                                                          \
      const float4 wl_ = wlo[(B) & 3];                                         \
      P_ = fmaf(ps[0], wl_.x, P_);                                             \
      P_ = fmaf(ps[1], wl_.y, P_);                                             \
      P_ = fmaf(ps[2], wl_.z, P_);                                             \
      if ((A) == 0 && (B) == 0) P_ = fmaf((m < 7) ? ps[3] : 0.0f, wl_.w, P_);  \
      else                      P_ = fmaf(ps[3], wl_.w, P_);                   \
    }                                                                          \
    {                                                                          \
      const float4 wh_ = whi[(B) & 3];                                         \
      if ((A) >= 1) {                                                          \
        if ((A) == 1 && (B) == 0) P_ = fmaf((m < 7) ? cs[0] : 0.0f, wh_.x, P_);\
        else                      P_ = fmaf(cs[0], wh_.x, P_);                 \
      }                                                                        \
      if ((A) >= 2) {                                                          \
        if ((A) == 2 && (B) == 0) P_ = fmaf((m < 7) ? cs[1] : 0.0f, wh_.y, P_);\
        else                      P_ = fmaf(cs[1], wh_.y, P_);                 \
      }                                                                        \
      if ((A) >= 3) {                                                          \
        if ((A) == 3 && (B) == 0) P_ = fmaf((m < 7) ? cs[2] : 0.0f, wh_.z, P_);\
        else                      P_ = fmaf(cs[2], wh_.z, P_);                 \
      }                                                                        \
      if ((B) >= 2)                                                            \
        P_ = fmaf((m < (B) - 1) ? cs[(A)] : 0.0f, F4C(wh_, (A)), P_);          \
    }                                                                          \
    P_ = fmaf((m == (((B) + 7) & 7)) ? s_prev : 0.0f, wapp[(B) & 3], P_);      \
    float t1_ = P_ + __shfl_xor(P_, 4);                                        \
    float t2_ = t1_ + dpp_xor2(t1_);                                           \
    const float T_ = t2_ + dpp_xor1(t2_);                                      \
    const float L_ = xwh[(B) & 1] + T_;                                        \
    const float tneg_ = L_ * NL2E;                                             \
    float s_ = (tneg_ < rth_cur) ? 1.0f : 0.0f;                                \
    const float mg_ = __builtin_fabsf(tneg_ - rth_cur);                        \
    if (__builtin_expect(!(mg_ >= 1e-3f), 0)) {                                \
      const double sd_ = 1.0 / (1.0 + exp(-(double)L_));                       \
      s_ = (uu[(B) & 1] < (float)sd_) ? 1.0f : 0.0f;                           \
    }                                                                          \
    if (m == 0) { xwl_row[i_] = L_; osr[i_] = s_; }                            \
    cs[(A)] = (m == (B)) ? s_ : cs[(A)];                                       \
    s_prev = s_;                                                               \
    rth_cur = rth_of(uu[((B) + 1) & 1]);                                       \
    {                                                                          \
      const int nx2_ = (i_ + 2 < OUT_F) ? i_ + 2 : OUT_F - 1;                  \
      xwh[(B) & 1] = xwl_row[nx2_];                                            \
      uu[(B) & 1] = uro[nx2_];                                                 \
    }                                                                          \
    {                                                                          \
      const int nx4_ = (i_ + 4 < OUT_F) ? i_ + 4 : OUT_F - 1;                  \
      const int th_ = (nx4_ >> 5) * 4;                                         \
      const int tlo_ = (th_ >= 4) ? th_ - 4 : 0;                               \
      const float* wr_ = wPermRow + (size_t)nx4_ * PR;                         \
      wlo[(B) & 3] = *(const float4*)(wr_ + tlo_);                             \
      whi[(B) & 3] = *(const float4*)(wr_ + th_);                              \
      wapp[(B) & 3] = wAppBase[(size_t)nx4_ * (W_K + 1)];                      \
    }                                                                          \
  } while (0)

#define SCAN_GROUP(PH, A) do {                                                 \
    SCAN_STEP(PH, A, 0); SCAN_STEP(PH, A, 1);                                  \
    SCAN_STEP(PH, A, 2); SCAN_STEP(PH, A, 3);                                  \
    SCAN_STEP(PH, A, 4); SCAN_STEP(PH, A, 5);                                  \
    SCAN_STEP(PH, A, 6); SCAN_STEP(PH, A, 7);                                  \
  } while (0)

// tail steps i = 1017..1023 (unchanged from r6)
#define SPEC_STEP(IO) do {                                                     \
    const int i_ = 1017 + (IO);                                                \
    const int o_ = 25 + (IO);                                                  \
    float P_ = F4C(opq[(o_ >> 2) & 1], o_ & 3);                                \
    {                                                                          \
      const float4 wl_ = wlo[o_ & 3];                                          \
      P_ = fmaf(ps[0], wl_.x, P_); P_ = fmaf(ps[1], wl_.y, P_);                \
      P_ = fmaf(ps[2], wl_.z, P_); P_ = fmaf(ps[3], wl_.w, P_);                \
    }                                                                          \
    {                                                                          \
      const float4 wh_ = whi[o_ & 3];                                          \
      P_ = fmaf(cs[0], wh_.x, P_); P_ = fmaf(cs[1], wh_.y, P_);                \
      P_ = fmaf(cs[2], wh_.z, P_);                                             \
    }                                                                          \
    float t1_ = P_ + __shfl_xor(P_, 4);                                        \
    float t2_ = t1_ + dpp_xor2(t1_);                                           \
    float T_ = t2_ + dpp_xor1(t2_);                                            \
    tl[(IO)] = s_prev;                                                         \
    T_ = fmaf(tl[0], twa.x, T_);                                               \
    if ((IO) >= 1) T_ = fmaf(tl[1], twa.y, T_);                                \
    if ((IO) >= 2) T_ = fmaf(tl[2], twa.z, T_);                                \
    if ((IO) >= 3) T_ = fmaf(tl[3], twa.w, T_);                                \
    if ((IO) >= 4) T_ = fmaf(tl[4], twb.x, T_);                                \
    if ((IO) >= 5) T_ = fmaf(tl[5], twb.y, T_);                                \
    if ((IO) >= 6) T_ = fmaf(tl[6], twb.z, T_);                                \
    const float L_ = xwh[o_ & 1] + T_;                                         \
    const float tneg_ = L_ * NL2E;                                             \
    float s_ = (tneg_ < rth_cur) ? 1.0f : 0.0f;                                \
    const float mg_ = __builtin_fabsf(tneg_ - rth_cur);                        \
    if (__builtin_expect(!(mg_ >= 1e-3f), 0)) {                                \
      const double sd_ = 1.0 / (1.0 + exp(-(double)L_));                       \
      s_ = (uu[o_ & 1] < (float)sd_) ? 1.0f : 0.0f;                            \
    }                                                                          \
    if (m == 0) { xwl_row[i_] = L_; osr[i_] = s_; }                            \
    s_prev = s_;                                                               \
    rth_cur = rth_of(uu[(o_ + 1) & 1]);                                        \
    {                                                                          \
      const int nx2_ = (i_ + 2 < OUT_F) ? i_ + 2 : OUT_F - 1;                  \
      xwh[o_ & 1] = xwl_row[nx2_]; uu[o_ & 1] = uro[nx2_];                     \
    }                                                                          \
    {                                                                          \
      const int nx4_ = (i_ + 4 < OUT_F) ? i_ + 4 : OUT_F - 1;                  \
      const float* wr_ = wPermRow + (size_t)nx4_ * PR;                         \
      wlo[o_ & 3] = *(const float4*)(wr_ + 120);                               \
      whi[o_ & 3] = *(const float4*)(wr_ + 124);                               \
    }                                                                          \
    if ((IO) < 6) {                                                            \
      twa = *(const float4*)(wTail + (i_ + 1) * 8);                            \
      twb = *(const float4*)(wTail + (i_ + 1) * 8 + 4);                        \
    }                                                                          \
  } while (0)

// bulk fold: one r-row's 4 ascending-t FMAs into acc[RR][0..3]
#define FOLD_RR(RR) do {                                                       \
    const h4 sv_ = *(const h4*)&smph[r0 + (RR)][mB][4 * c];                    \
    _Pragma("unroll")                                                          \
    for (int ii = 0; ii < 4; ++ii) {                                           \
      acc[(RR)][ii] = fmaf((float)sv_[0], F4C(wq0, ii), acc[(RR)][ii]);        \
      acc[(RR)][ii] = fmaf((float)sv_[1], F4C(wq1, ii), acc[(RR)][ii]);        \
      acc[(RR)][ii] = fmaf((float)sv_[2], F4C(wq2, ii), acc[(RR)][ii]);        \
      acc[(RR)][ii] = fmaf((float)sv_[3], F4C(wq3, ii), acc[(RR)][ii]);        \
    }                                                                          \
  } while (0)

// ---------------------------------------------------------------------------
// K2: checkpointed scan, 16 rows/block. Waves 0-1: scan (8 rows each, r6's
// verified step macros). Waves 2-5: bulk checkpoint GEMM for phase p+1 —
// register tile 4i x 4r x 1m per thread, ascending-t fmaf chains = exact
// reference-chain prefixes. w staged per-wave (wave-private 1KB slab/chunk)
// from coalesced wPermT; samples fp16 in LDS [r][m][136]. One barrier/phase.
// ---------------------------------------------------------------------------
__global__ __launch_bounds__(384) void k_scan32(const float* __restrict__ w,
                                                const float* __restrict__ u,
                                                const float* __restrict__ wPerm,
                                                const float* __restrict__ wTail,
                                                const float* __restrict__ wPermT,
                                                float* xwl,
                                                float* __restrict__ out_s) {
  __shared__ _Float16 smph[ROWS][8][SR];     // 34816 B samples
  __shared__ float oldp[2][8][ROWS][8][4];   // 32768 B checkpoints
  __shared__ float wch[4][4][8][8];          //  4096 B per-wave w slabs

  const int tid = threadIdx.x;
  const int wid = tid >> 6;
  const int lane = tid & 63;
  const int g = lane >> 3, m = lane & 7;
  const float NL2E = -1.44269504088896340736f;

  // zero oldp buf0 (phase-0 scan reads it: empty prefix)
  {
    float* z = &oldp[0][0][0][0][0];
    for (int k = tid; k < 8 * ROWS * 8 * 4; k += 384) z[k] = 0.0f;
  }
  __syncthreads();

  // ---------------- scan state (waves 0,1) ----------------
  const int rl = wid * 8 + g;                       // row-local 0..15 (scan)
  const int r = blockIdx.x * ROWS + rl;
  float* xwl_row = xwl + (size_t)r * OUT_F;         // xw in, logits out
  const float* uro = u + (size_t)r * OUT_F;
  float* osr = out_s + (size_t)r * OUT_F;

  float4 wlo[4], whi[4], opq[2];
  float wapp[4], xwh[2], uu[2];
  float ps[4], cs[4], tl[7];
  float rth_cur = 0.0f, s_prev = 0.0f;
  const float* wPermRow = wPerm + m * 132;
  const float* wAppBase = w + (IN_F - 1);   // wAppBase[i*(W_K+1)] = w[i][512+i-1]

  if (wid < 2) {
#pragma unroll
    for (int c = 0; c < 4; ++c) { ps[c] = 0.0f; cs[c] = 0.0f; }
#pragma unroll
    for (int c = 0; c < 7; ++c) tl[c] = 0.0f;
#pragma unroll
    for (int b = 0; b < 4; ++b) {
      const float* wr_ = wPermRow + (size_t)b * PR;
      wlo[b] = *(const float4*)(wr_);
      whi[b] = *(const float4*)(wr_);
      wapp[b] = (b == 0) ? 0.0f : wAppBase[(size_t)b * (W_K + 1)];
    }
    xwh[0] = xwl_row[0]; xwh[1] = xwl_row[1];
    uu[0] = uro[0]; uu[1] = uro[1];
    rth_cur = rth_of(uu[0]);
  }

  // ---------------- bulk constants (waves 2..5) ----------------
  const int bt = tid - 128;                // 0..255 (valid when wid>=2)
  const int wv = bt >> 6;                  // 0..3  bulk wave id
  const int mB = bt & 7;
  const int r0 = ((bt >> 3) & 3) * 4;
  const int ibase = ((bt >> 5) & 1) * 4;   // i within wave slab
  const int qv = bt >> 5;                  // i-quad 0..7 (== 2*wv + half)
  const int ltt = (bt & 63) >> 4;          // staging: t-subindex
  const int lq = bt & 15;                  // staging: float4 index
  const int li = lq >> 1, m0 = (lq & 1) * 4;
  float* wchw = &wch[wv][0][0][0];         // [tt][m][i] floats

  for (int p = 0; p < 31; ++p) {
    if (wid < 2) {
      // -------- scan phase p: steps 32p .. 32p+31 --------
      opq[0] = *(const float4*)&oldp[p & 1][0][rl][m][0];
      SCAN_GROUP(p, 0); SCAN_GROUP(p, 1); SCAN_GROUP(p, 2); SCAN_GROUP(p, 3);
      // publish this block's samples (t = 4p..4p+3) packed b64, and roll
      h4 hv;
      hv[0] = (_Float16)cs[0]; hv[1] = (_Float16)cs[1];
      hv[2] = (_Float16)cs[2]; hv[3] = (_Float16)cs[3];
      *(h4*)&smph[rl][m][4 * p] = hv;
#pragma unroll
      for (int k = 0; k < 4; ++k) ps[k] = cs[k];
    } else {
      // -------- bulk: checkpoints for phase p+1 (fold t < 4p) --------
      const int i0win = 32 * (p + 1);
      float acc[4][4];
#pragma unroll
      for (int a = 0; a < 4; ++a)
#pragma unroll
        for (int b = 0; b < 4; ++b) acc[a][b] = 0.0f;

      const float* gbase = wPermT +
          (((size_t)ltt * OUT_F + i0win + 8 * wv + li) * 8 + m0);
      float4 stg{};
      if (p > 0) stg = *(const float4*)gbase;
      for (int c = 0; c < p; ++c) {
        float4 nxt{};
        if (c + 1 < p)
          nxt = *(const float4*)(gbase + (size_t)(c + 1) * (4 * OUT_F * 8));
        // park slab c (wave-private; same-wave ds order guarantees visibility)
        wchw[(ltt * 8 + m0 + 0) * 8 + li] = stg.x;
        wchw[(ltt * 8 + m0 + 1) * 8 + li] = stg.y;
        wchw[(ltt * 8 + m0 + 2) * 8 + li] = stg.z;
        wchw[(ltt * 8 + m0 + 3) * 8 + li] = stg.w;
        const float4 wq0 = *(const float4*)&wchw[(0 * 8 + mB) * 8 + ibase];
        const float4 wq1 = *(const float4*)&wchw[(1 * 8 + mB) * 8 + ibase];
        const float4 wq2 = *(const float4*)&wchw[(2 * 8 + mB) * 8 + ibase];
        const float4 wq3 = *(const float4*)&wchw[(3 * 8 + mB) * 8 + ibase];
        FOLD_RR(0); FOLD_RR(1); FOLD_RR(2); FOLD_RR(3);
        stg = nxt;
      }
      const int nb = (p + 1) & 1;
#pragma unroll
      for (int rr = 0; rr < 4; ++rr) {
        float4 v;
        v.x = acc[rr][0]; v.y = acc[rr][1]; v.z = acc[rr][2]; v.w = acc[rr][3];
        *(float4*)&oldp[nb][qv][r0 + rr][mB][0] = v;
      }
    }
    block_sync_lds();
  }

  if (wid < 2) {
    // -------- phase 31: steps 992..1016 generic, 1017..1023 tail --------
    opq[0] = *(const float4*)&oldp[1][0][rl][m][0];
    SCAN_GROUP(31, 0); SCAN_GROUP(31, 1); SCAN_GROUP(31, 2);
    SCAN_STEP(31, 3, 0);   // i = 1016
    float4 twa = *(const float4*)(wTail + 1017 * 8);
    float4 twb = *(const float4*)(wTail + 1017 * 8 + 4);
    SPEC_STEP(0); SPEC_STEP(1); SPEC_STEP(2); SPEC_STEP(3);
    SPEC_STEP(4); SPEC_STEP(5); SPEC_STEP(6);
  }
}

// ---------------------------------------------------------------------------
extern "C" void kernel_launch(void* const* d_in, const int* in_sizes, int n_in,
                              void* d_out, int out_size, void* d_ws, size_t ws_size,
                              hipStream_t stream) {
  float* out_s = (float*)d_out;                      // samples (B x OUT_F) fp32
  float* out_l = out_s + (size_t)BATCH * OUT_F;      // logits  (B x OUT_F) fp32
  const int nfill = (BATCH * OUT_F) / (256 * 4);

  const bool shapes_ok =
      n_in == 4 &&
      in_sizes[0] == BATCH * IN_F && in_sizes[1] == OUT_F * W_K &&
      in_sizes[2] == OUT_F && in_sizes[3] == BATCH * OUT_F &&
      out_size == 2 * BATCH * OUT_F;
  if (!shapes_ok) {
    k_fill<<<nfill, 256, 0, stream>>>(out_s, 11.0f);
    return;
  }

  const size_t perm_bytes =
      ((size_t)OUT_F * PR + (size_t)OUT_F * 8 + (size_t)128 * OUT_F * 8) *
      sizeof(float);   // wPerm + wTail + wPermT ~ 8.4 MiB
  if (ws_size < perm_bytes) {
    k_fill<<<nfill, 256, 0, stream>>>(out_s, 7.0f);
    return;
  }

  const float* x = (const float*)d_in[0];     // fp32 (8192 x 512)
  const float* w = (const float*)d_in[1];     // fp32 (1024 x 1535)
  const float* bias = (const float*)d_in[2];  // fp32 (1024)
  const float* u = (const float*)d_in[3];     // fp32 (8192 x 1024)
  float* wPerm = (float*)d_ws;                          // 4.3 MiB
  float* wTail = wPerm + (size_t)OUT_F * PR;            // 32 KiB
  float* wPermT = wTail + (size_t)OUT_F * 8;            // 4.0 MiB

  k_gemm32<<<dim3(BATCH / 64, OUT_F / 64), 256, 0, stream>>>(x, w, bias, out_l);
  k_perm<<<OUT_F, 256, 0, stream>>>(w, wPerm, wTail, wPermT);
  k_scan32<<<BATCH / ROWS, 384, 0, stream>>>(w, u, wPerm, wTail, wPermT,
                                             out_l, out_s);
}